// Round 12
// baseline (2557.727 us; speedup 1.0000x reference)
//
#include <hip/hip_runtime.h>

// ---------------------------------------------------------------------------
// MutualRec forward: 5x GATv2 + ChebConv(k=3) + mutualistic MLP + edge dots
// R12: GEMM family = W-in-VGPRs, zero-LDS, zero-barrier "mm" kernels.
//   Lane j holds W column j (64 VGPR). X rows stream in as 1 coalesced
//   dword/lane (vmcnt path); broadcast via v_readlane (VALU, no LDS pipe).
//   mm11: Y = X@W (+b | +=) ; mm12: 2 outputs, 1 X stream ; mm21: 2 X -> 1 Y.
//   Graph kernels (CSR GAT/cheb), dots, sorts unchanged from R10 (1778us).
// ---------------------------------------------------------------------------

#define LRELU_SLOPE 0.2f
#define MM_BLOCKS 2048
#define EDGE_BLOCKS 2048

__device__ __forceinline__ float rl(float v, int k) {
  return __int_as_float(__builtin_amdgcn_readlane(__float_as_int(v), k));
}

// ============================ GEMM family (mm) =============================
// mm11: Y[N,64] = X@W + b  (ACC: Y += X@W, b ignored)
template <bool ACC>
__global__ void mm11_k(const float* __restrict__ X, const float* __restrict__ W,
                       const float* __restrict__ b, float* __restrict__ Y, int N) {
  const int lane = threadIdx.x & 63;
  const int gw = (blockIdx.x * blockDim.x + threadIdx.x) >> 6;
  const int nw = (gridDim.x * blockDim.x) >> 6;
  float w[64];
#pragma unroll
  for (int k = 0; k < 64; ++k) w[k] = W[k * 64 + lane];
  const float bj = ACC ? 0.0f : b[lane];
  for (int q = gw * 4; q < N; q += nw * 4) {
    const int r1 = (q + 1 < N) ? q + 1 : q;
    const int r2 = (q + 2 < N) ? q + 2 : q;
    const int r3 = (q + 3 < N) ? q + 3 : q;
    const float x0 = X[(size_t)q * 64 + lane];
    const float x1 = X[(size_t)r1 * 64 + lane];
    const float x2 = X[(size_t)r2 * 64 + lane];
    const float x3 = X[(size_t)r3 * 64 + lane];
    float y0, y1, y2, y3;
    if (ACC) {
      y0 = Y[(size_t)q * 64 + lane];
      y1 = Y[(size_t)r1 * 64 + lane];
      y2 = Y[(size_t)r2 * 64 + lane];
      y3 = Y[(size_t)r3 * 64 + lane];
    } else {
      y0 = bj; y1 = bj; y2 = bj; y3 = bj;
    }
#pragma unroll
    for (int k = 0; k < 64; ++k) {
      const float wk = w[k];
      y0 = fmaf(rl(x0, k), wk, y0);
      y1 = fmaf(rl(x1, k), wk, y1);
      y2 = fmaf(rl(x2, k), wk, y2);
      y3 = fmaf(rl(x3, k), wk, y3);
    }
    Y[(size_t)q * 64 + lane] = y0;
    if (q + 1 < N) Y[(size_t)(q + 1) * 64 + lane] = y1;
    if (q + 2 < N) Y[(size_t)(q + 2) * 64 + lane] = y2;
    if (q + 3 < N) Y[(size_t)(q + 3) * 64 + lane] = y3;
  }
}

// mm12: Y0 = X@W0 + b0 ; Y1 = X@W1 + b1 (one X stream, readlanes shared)
__global__ void mm12_k(const float* __restrict__ X,
                       const float* __restrict__ W0, const float* __restrict__ W1,
                       const float* __restrict__ b0, const float* __restrict__ b1,
                       float* __restrict__ Y0, float* __restrict__ Y1, int N) {
  const int lane = threadIdx.x & 63;
  const int gw = (blockIdx.x * blockDim.x + threadIdx.x) >> 6;
  const int nw = (gridDim.x * blockDim.x) >> 6;
  float wa[64], wb[64];
#pragma unroll
  for (int k = 0; k < 64; ++k) wa[k] = W0[k * 64 + lane];
#pragma unroll
  for (int k = 0; k < 64; ++k) wb[k] = W1[k * 64 + lane];
  const float bj0 = b0[lane], bj1 = b1[lane];
  for (int q = gw * 4; q < N; q += nw * 4) {
    const int r1 = (q + 1 < N) ? q + 1 : q;
    const int r2 = (q + 2 < N) ? q + 2 : q;
    const int r3 = (q + 3 < N) ? q + 3 : q;
    const float x0 = X[(size_t)q * 64 + lane];
    const float x1 = X[(size_t)r1 * 64 + lane];
    const float x2 = X[(size_t)r2 * 64 + lane];
    const float x3 = X[(size_t)r3 * 64 + lane];
    float y0 = bj0, y1 = bj0, y2 = bj0, y3 = bj0;
    float z0 = bj1, z1 = bj1, z2 = bj1, z3 = bj1;
#pragma unroll
    for (int k = 0; k < 64; ++k) {
      const float wk0 = wa[k], wk1 = wb[k];
      const float s0 = rl(x0, k), s1 = rl(x1, k), s2 = rl(x2, k), s3 = rl(x3, k);
      y0 = fmaf(s0, wk0, y0); z0 = fmaf(s0, wk1, z0);
      y1 = fmaf(s1, wk0, y1); z1 = fmaf(s1, wk1, z1);
      y2 = fmaf(s2, wk0, y2); z2 = fmaf(s2, wk1, z2);
      y3 = fmaf(s3, wk0, y3); z3 = fmaf(s3, wk1, z3);
    }
    Y0[(size_t)q * 64 + lane] = y0;
    Y1[(size_t)q * 64 + lane] = z0;
    if (q + 1 < N) { Y0[(size_t)(q + 1) * 64 + lane] = y1; Y1[(size_t)(q + 1) * 64 + lane] = z1; }
    if (q + 2 < N) { Y0[(size_t)(q + 2) * 64 + lane] = y2; Y1[(size_t)(q + 2) * 64 + lane] = z2; }
    if (q + 3 < N) { Y0[(size_t)(q + 3) * 64 + lane] = y3; Y1[(size_t)(q + 3) * 64 + lane] = z3; }
  }
}

// mm21: Y = X0@W0 + X1@W1 + b (two X streams, one output)
__global__ void mm21_k(const float* __restrict__ X0, const float* __restrict__ W0,
                       const float* __restrict__ X1, const float* __restrict__ W1,
                       const float* __restrict__ b, float* __restrict__ Y, int N) {
  const int lane = threadIdx.x & 63;
  const int gw = (blockIdx.x * blockDim.x + threadIdx.x) >> 6;
  const int nw = (gridDim.x * blockDim.x) >> 6;
  float wa[64], wb[64];
#pragma unroll
  for (int k = 0; k < 64; ++k) wa[k] = W0[k * 64 + lane];
#pragma unroll
  for (int k = 0; k < 64; ++k) wb[k] = W1[k * 64 + lane];
  const float bj = b[lane];
  for (int q = gw * 4; q < N; q += nw * 4) {
    const int r1 = (q + 1 < N) ? q + 1 : q;
    const int r2 = (q + 2 < N) ? q + 2 : q;
    const int r3 = (q + 3 < N) ? q + 3 : q;
    const float a0 = X0[(size_t)q * 64 + lane];
    const float a1 = X0[(size_t)r1 * 64 + lane];
    const float a2 = X0[(size_t)r2 * 64 + lane];
    const float a3 = X0[(size_t)r3 * 64 + lane];
    const float c0 = X1[(size_t)q * 64 + lane];
    const float c1 = X1[(size_t)r1 * 64 + lane];
    const float c2 = X1[(size_t)r2 * 64 + lane];
    const float c3 = X1[(size_t)r3 * 64 + lane];
    float y0 = bj, y1 = bj, y2 = bj, y3 = bj;
#pragma unroll
    for (int k = 0; k < 64; ++k) {
      const float wk0 = wa[k], wk1 = wb[k];
      y0 = fmaf(rl(a0, k), wk0, y0);
      y1 = fmaf(rl(a1, k), wk0, y1);
      y2 = fmaf(rl(a2, k), wk0, y2);
      y3 = fmaf(rl(a3, k), wk0, y3);
      y0 = fmaf(rl(c0, k), wk1, y0);
      y1 = fmaf(rl(c1, k), wk1, y1);
      y2 = fmaf(rl(c2, k), wk1, y2);
      y3 = fmaf(rl(c3, k), wk1, y3);
    }
    Y[(size_t)q * 64 + lane] = y0;
    if (q + 1 < N) Y[(size_t)(q + 1) * 64 + lane] = y1;
    if (q + 2 < N) Y[(size_t)(q + 2) * 64 + lane] = y2;
    if (q + 3 < N) Y[(size_t)(q + 3) * 64 + lane] = y3;
  }
}

// ========================= CSR build (counting sort) =======================
__global__ void hist_k(const int* __restrict__ key, int* __restrict__ cnt, int E) {
  const int e = blockIdx.x * blockDim.x + threadIdx.x;
  if (e < E) atomicAdd(cnt + key[e], 1);
}

__global__ void scan1_k(const int* __restrict__ in, int* __restrict__ out,
                        int* __restrict__ bsum, int n) {
  __shared__ int tmp[256];
  const int t = threadIdx.x;
  const int base = blockIdx.x * 1024 + t * 4;
  int v0 = (base + 0 < n) ? in[base + 0] : 0;
  int v1 = (base + 1 < n) ? in[base + 1] : 0;
  int v2 = (base + 2 < n) ? in[base + 2] : 0;
  int v3 = (base + 3 < n) ? in[base + 3] : 0;
  const int s = v0 + v1 + v2 + v3;
  tmp[t] = s;
  __syncthreads();
  for (int off = 1; off < 256; off <<= 1) {
    const int x = (t >= off) ? tmp[t - off] : 0;
    __syncthreads();
    tmp[t] += x;
    __syncthreads();
  }
  const int excl = tmp[t] - s;
  if (t == 255) bsum[blockIdx.x] = tmp[255];
  if (base + 0 < n) out[base + 0] = excl;
  if (base + 1 < n) out[base + 1] = excl + v0;
  if (base + 2 < n) out[base + 2] = excl + v0 + v1;
  if (base + 3 < n) out[base + 3] = excl + v0 + v1 + v2;
}
__global__ void scan2_k(int* __restrict__ bsum, int nb) {
  if (threadIdx.x == 0) {
    int acc = 0;
    for (int i = 0; i < nb; ++i) { const int v = bsum[i]; bsum[i] = acc; acc += v; }
  }
}
__global__ void scan3_k(int* __restrict__ out, const int* __restrict__ bsum, int n) {
  const int i = blockIdx.x * blockDim.x + threadIdx.x;
  if (i < n) out[i] += bsum[i >> 10];
}

__global__ void scatter_k(const int* __restrict__ key, const int* __restrict__ other,
                          int* __restrict__ cursor, int* __restrict__ srt, int E) {
  const int e = blockIdx.x * blockDim.x + threadIdx.x;
  if (e < E) {
    const int p = atomicAdd(cursor + key[e], 1);
    srt[p] = other[e];
  }
}

// ======================= CSR-based graph kernels ===========================
__global__ void gat_csr_k(const float* __restrict__ fs, const float* __restrict__ fd,
                          const float* __restrict__ attn,
                          const int* __restrict__ rowptr, const int* __restrict__ nbr,
                          float* __restrict__ out, int N) {
  const int lane = threadIdx.x & 63;
  const int wid = (blockIdx.x * blockDim.x + threadIdx.x) >> 6;
  const int nw = (gridDim.x * blockDim.x) >> 6;
  const float aw = attn[lane];
  for (int n = wid; n < N; n += nw) {
    const int beg = rowptr[n], end = rowptr[n + 1];
    const float fdv = fd[(size_t)n * 64 + lane];
    float acc = 0.0f, den = 0.0f;
    int e = beg;
    for (; e + 1 < end; e += 2) {
      const int s0 = nbr[e], s1 = nbr[e + 1];
      const float f0 = fs[(size_t)s0 * 64 + lane];
      const float f1 = fs[(size_t)s1 * 64 + lane];
      float v0 = f0 + fdv; v0 = v0 > 0.0f ? v0 : LRELU_SLOPE * v0;
      float v1 = f1 + fdv; v1 = v1 > 0.0f ? v1 : LRELU_SLOPE * v1;
      float p0 = v0 * aw, p1 = v1 * aw;
#pragma unroll
      for (int o = 32; o; o >>= 1) {
        p0 += __shfl_xor(p0, o, 64);
        p1 += __shfl_xor(p1, o, 64);
      }
      const float e0 = __expf(p0), e1 = __expf(p1);
      den += e0 + e1;
      acc = fmaf(e0, f0, acc);
      acc = fmaf(e1, f1, acc);
    }
    if (e < end) {
      const int s0 = nbr[e];
      const float f0 = fs[(size_t)s0 * 64 + lane];
      float v0 = f0 + fdv; v0 = v0 > 0.0f ? v0 : LRELU_SLOPE * v0;
      float p0 = v0 * aw;
#pragma unroll
      for (int o = 32; o; o >>= 1) p0 += __shfl_xor(p0, o, 64);
      const float e0 = __expf(p0);
      den += e0;
      acc = fmaf(e0, f0, acc);
    }
    const float inv = den > 0.0f ? 1.0f / den : 0.0f;
    out[(size_t)n * 64 + lane] = acc * inv;
  }
}

// Fused Cheb step (MODE 1: T1; MODE 2: T2)
template <int MODE>
__global__ void cheb_csr_k(const float* __restrict__ x, const float* __restrict__ T0,
                           const float* __restrict__ Tp, const float* __restrict__ dinv,
                           const float* __restrict__ lam,
                           const int* __restrict__ rowptr, const int* __restrict__ nbr,
                           float* __restrict__ outT, int N) {
  const float re = 2.0f / lam[0];
  const int lane = threadIdx.x & 63;
  const int wid = (blockIdx.x * blockDim.x + threadIdx.x) >> 6;
  const int nw = (gridDim.x * blockDim.x) >> 6;
  for (int n = wid; n < N; n += nw) {
    const int beg = rowptr[n], end = rowptr[n + 1];
    float acc = 0.0f;
    int e = beg;
    for (; e + 1 < end; e += 2) {
      const int s0 = nbr[e], s1 = nbr[e + 1];
      acc = fmaf(x[(size_t)s0 * 64 + lane], dinv[s0], acc);
      acc = fmaf(x[(size_t)s1 * 64 + lane], dinv[s1], acc);
    }
    if (e < end) {
      const int s0 = nbr[e];
      acc = fmaf(x[(size_t)s0 * 64 + lane], dinv[s0], acc);
    }
    const float hv = acc * dinv[n];
    float r;
    if (MODE == 1) {
      r = -re * hv + (re - 1.0f) * T0[(size_t)n * 64 + lane];
    } else {
      r = -2.0f * re * hv + 2.0f * (re - 1.0f) * Tp[(size_t)n * 64 + lane]
          - T0[(size_t)n * 64 + lane];
    }
    outT[(size_t)n * 64 + lane] = r;
  }
}

__global__ void dinv_k(const int* __restrict__ rowptr, float* __restrict__ dinv, int N) {
  const int i = blockIdx.x * blockDim.x + threadIdx.x;
  if (i < N) {
    const float deg = (float)(rowptr[i + 1] - rowptr[i]);
    dinv[i] = rsqrtf(fmaxf(deg, 1.0f));
  }
}

// ---- mutualistic ----
__global__ void mut_k(const float* __restrict__ hP, const float* __restrict__ hS,
                      float* __restrict__ mP, float* __restrict__ mS, int N) {
  const int lane = threadIdx.x & 63;
  const int u = (blockIdx.x * blockDim.x + threadIdx.x) >> 6;
  if (u >= N) return;
  const float p = hP[(size_t)u * 64 + lane];
  const float s = hS[(size_t)u * 64 + lane];
  const float m = p * s;
  float mxp = p, mxs = s;
#pragma unroll
  for (int o = 32; o; o >>= 1) {
    mxp = fmaxf(mxp, __shfl_xor(mxp, o, 64));
    mxs = fmaxf(mxs, __shfl_xor(mxs, o, 64));
  }
  const float ep = __expf(p - mxp);
  const float es = __expf(s - mxs);
  float sp = ep, ss = es;
#pragma unroll
  for (int o = 32; o; o >>= 1) {
    sp += __shfl_xor(sp, o, 64);
    ss += __shfl_xor(ss, o, 64);
  }
  mP[(size_t)u * 64 + lane] = m * (ep / sp);
  mS[(size_t)u * 64 + lane] = m * (es / ss);
}

// ---- edge dot (edge-list, ILP-2) ----
__global__ void dot_k(const float* __restrict__ A, const float* __restrict__ Bm,
                      const int* __restrict__ src, const int* __restrict__ dst,
                      float* __restrict__ out, int E) {
  const int lane = threadIdx.x & 63;
  const int wid = (blockIdx.x * blockDim.x + threadIdx.x) >> 6;
  const int nw = (gridDim.x * blockDim.x) >> 6;
  for (int e0 = wid * 2; e0 < E; e0 += nw * 2) {
    const bool has1 = (e0 + 1 < E);
    const int s0 = src[e0], d0 = dst[e0];
    const int s1 = has1 ? src[e0 + 1] : s0;
    const int d1 = has1 ? dst[e0 + 1] : d0;
    float p0 = A[(size_t)s0 * 64 + lane] * Bm[(size_t)d0 * 64 + lane];
    float p1 = A[(size_t)s1 * 64 + lane] * Bm[(size_t)d1 * 64 + lane];
#pragma unroll
    for (int o = 32; o; o >>= 1) {
      p0 += __shfl_xor(p0, o, 64);
      p1 += __shfl_xor(p1, o, 64);
    }
    if (lane == 0) {
      out[e0] = p0;
      if (has1) out[e0 + 1] = p1;
    }
  }
}

// ---------------------------------------------------------------------------

static void build_csr(const int* key, const int* other, int E, int N,
                      int* rowptr, int* srt, int* cursor, int* bsum,
                      hipStream_t stream) {
  const int n1 = N + 1;
  hipMemsetAsync(cursor, 0, (size_t)n1 * 4, stream);
  hist_k<<<(E + 255) / 256, 256, 0, stream>>>(key, cursor, E);
  const int nb = (n1 + 1023) / 1024;
  scan1_k<<<nb, 256, 0, stream>>>(cursor, rowptr, bsum, n1);
  scan2_k<<<1, 64, 0, stream>>>(bsum, nb);
  scan3_k<<<(n1 + 255) / 256, 256, 0, stream>>>(rowptr, bsum, n1);
  hipMemcpyAsync(cursor, rowptr, (size_t)N * 4, hipMemcpyDeviceToDevice, stream);
  scatter_k<<<(E + 255) / 256, 256, 0, stream>>>(key, other, cursor, srt, E);
}

extern "C" void kernel_launch(void* const* d_in, const int* in_sizes, int n_in,
                              void* d_out, int out_size, void* d_ws, size_t ws_size,
                              hipStream_t stream) {
  const float* user_emb = (const float*)d_in[0];
  const float* item_emb = (const float*)d_in[1];
  const int* rate_src = (const int*)d_in[2];
  const int* rate_dst = (const int*)d_in[3];
  const int* link_src = (const int*)d_in[4];
  const int* link_dst = (const int*)d_in[5];
  const int* neg_rate_src = (const int*)d_in[6];
  const int* neg_rate_dst = (const int*)d_in[7];
  const int* neg_link_src = (const int*)d_in[8];
  const int* neg_link_dst = (const int*)d_in[9];
  const float* lam = (const float*)d_in[10];
  const float* gat_Wsrc = (const float*)d_in[11];
  const float* gat_bsrc = (const float*)d_in[12];
  const float* gat_Wdst = (const float*)d_in[13];
  const float* gat_bdst = (const float*)d_in[14];
  const float* gat_attn = (const float*)d_in[15];
  const float* W_out = (const float*)d_in[16];
  const float* b_out = (const float*)d_in[17];
  const float* cheb_W = (const float*)d_in[18];
  const float* cheb_b = (const float*)d_in[19];
  const float* Wc = (const float*)d_in[20];
  const float* bc = (const float*)d_in[21];
  const float* Wsm = (const float*)d_in[22];
  const float* bs = (const float*)d_in[23];
  const float* WpP = (const float*)d_in[24];
  const float* bpP = (const float*)d_in[25];
  const float* WpS = (const float*)d_in[26];
  const float* bpS = (const float*)d_in[27];

  const int NU = in_sizes[0] / 64;
  const int NI = in_sizes[1] / 64;
  const int NR = in_sizes[2];
  const int NL = in_sizes[4];
  const int NMAX = NU > NI ? NU : NI;
  const size_t MAT = (size_t)NMAX * 64;

  float* ws = (float*)d_ws;
  float* B0 = ws + 0 * MAT;
  float* B1 = ws + 1 * MAT;
  float* B2 = ws + 2 * MAT;
  float* B3 = ws + 3 * MAT;
  float* B4 = ws + 4 * MAT;
  float* B5 = ws + 5 * MAT;
  float* B6 = ws + 6 * MAT;
  float* B7 = ws + 7 * MAT;
  int* ip = (int*)(ws + 8 * MAT);
  int* rp_rd = ip;                   // NI+1
  int* rp_rs = rp_rd + (NI + 1);     // NU+1
  int* rp_ld = rp_rs + (NU + 1);     // NU+1
  int* srt_rd = rp_ld + (NU + 1);    // NR
  int* srt_rs = srt_rd + NR;         // NR
  int* srt_ld = srt_rs + NR;         // NL
  int* cursor = srt_ld + NL;         // NMAX+1
  int* bsum = cursor + (NMAX + 1);   // 256
  float* dinv = (float*)(bsum + 256);  // NU

  const int W64 = 64 * 64, B64 = 64;

  // ---- 3 CSR groupings ----
  build_csr(rate_dst, rate_src, NR, NI, rp_rd, srt_rd, cursor, bsum, stream);
  build_csr(rate_src, rate_dst, NR, NU, rp_rs, srt_rs, cursor, bsum, stream);
  build_csr(link_dst, link_src, NL, NU, rp_ld, srt_ld, cursor, bsum, stream);

  // ---- user projections: fs0->B0, fd1->B1 ; fd2->B2, fd3->B3 ----
  mm12_k<<<MM_BLOCKS, 256, 0, stream>>>(
      user_emb, gat_Wsrc + 0 * W64, gat_Wdst + 1 * W64,
      gat_bsrc + 0 * B64, gat_bdst + 1 * B64, B0, B1, NU);
  mm12_k<<<MM_BLOCKS, 256, 0, stream>>>(
      user_emb, gat_Wdst + 2 * W64, gat_Wdst + 3 * W64,
      gat_bdst + 2 * B64, gat_bdst + 3 * B64, B2, B3, NU);
  // ---- item projections: fd0->B4, fs1->B5 ----
  mm12_k<<<MM_BLOCKS, 256, 0, stream>>>(
      item_emb, gat_Wdst + 0 * W64, gat_Wsrc + 1 * W64,
      gat_bdst + 0 * B64, gat_bsrc + 1 * B64, B4, B5, NI);

  // ---- gat0: (fs=B0, fd=B4) over rate-by-item -> B6 (h1_item) ----
  gat_csr_k<<<EDGE_BLOCKS, 256, 0, stream>>>(B0, B4, gat_attn + 0 * B64, rp_rd, srt_rd, B6, NI);
  // ---- gat1: (fs=B5, fd=B1) over rate-by-user -> B7 (h2_user) ----
  gat_csr_k<<<EDGE_BLOCKS, 256, 0, stream>>>(B5, B1, gat_attn + 1 * B64, rp_rs, srt_rs, B7, NU);

  // ---- fs2 = h1_item @ Ws2 -> B0 ; gat2 (fs=B0, fd=B2) -> B4 (item_infl) ----
  mm11_k<false><<<MM_BLOCKS, 256, 0, stream>>>(B6, gat_Wsrc + 2 * W64, gat_bsrc + 2 * B64, B0, NI);
  gat_csr_k<<<EDGE_BLOCKS, 256, 0, stream>>>(B0, B2, gat_attn + 2 * B64, rp_rs, srt_rs, B4, NU);

  // ---- fs3 = h2_user @ Ws3 -> B5 ; gat3 (fs=B5, fd=B3) -> B2 (social_item) ----
  mm11_k<false><<<MM_BLOCKS, 256, 0, stream>>>(B7, gat_Wsrc + 3 * W64, gat_bsrc + 3 * B64, B5, NU);
  gat_csr_k<<<EDGE_BLOCKS, 256, 0, stream>>>(B5, B3, gat_attn + 3 * B64, rp_ld, srt_ld, B2, NU);

  // ---- user_pref = [item_infl(B4), social_item(B2)] @ W_out + b_out -> B0 ----
  mm21_k<<<MM_BLOCKS, 256, 0, stream>>>(B4, W_out, B2, W_out + 64 * 64, b_out, B0, NU);

  // ---- ChebConv(k=3): T1->B5, T2->B3, rst->B6 ----
  dinv_k<<<(NU + 255) / 256, 256, 0, stream>>>(rp_ld, dinv, NU);
  cheb_csr_k<1><<<EDGE_BLOCKS, 256, 0, stream>>>(user_emb, user_emb, nullptr, dinv, lam,
                                                 rp_ld, srt_ld, B5, NU);
  cheb_csr_k<2><<<EDGE_BLOCKS, 256, 0, stream>>>(B5, user_emb, B5, dinv, lam,
                                                 rp_ld, srt_ld, B3, NU);
  mm21_k<<<MM_BLOCKS, 256, 0, stream>>>(user_emb, cheb_W + 0 * W64, B5, cheb_W + 1 * W64,
                                        cheb_b, B6, NU);
  mm11_k<true><<<MM_BLOCKS, 256, 0, stream>>>(B3, cheb_W + 2 * W64, nullptr, B6, NU);

  // ---- rst projections: fs4->B4, fd4->B2 ; gat4 -> B5 (user_social) ----
  mm12_k<<<MM_BLOCKS, 256, 0, stream>>>(
      B6, gat_Wsrc + 4 * W64, gat_Wdst + 4 * W64,
      gat_bsrc + 4 * B64, gat_bdst + 4 * B64, B4, B2, NU);
  gat_csr_k<<<EDGE_BLOCKS, 256, 0, stream>>>(B4, B2, gat_attn + 4 * B64, rp_ld, srt_ld, B5, NU);

  // ---- mutualistic ----
  mm21_k<<<MM_BLOCKS, 256, 0, stream>>>(B0, Wc, user_emb, Wc + 64 * 64, bc, B4, NU);   // h_uP
  mm21_k<<<MM_BLOCKS, 256, 0, stream>>>(B5, Wsm, user_emb, Wsm + 64 * 64, bs, B2, NU); // h_uS
  mut_k<<<(NU + 3) / 4, 256, 0, stream>>>(B4, B2, B3, B7, NU);  // mP->B3, mS->B7
  mm21_k<<<MM_BLOCKS, 256, 0, stream>>>(B3, WpP, B4, WpP + 64 * 64, bpP, B0, NU);  // h_new_P
  mm21_k<<<MM_BLOCKS, 256, 0, stream>>>(B7, WpS, B2, WpS + 64 * 64, bpS, B5, NU);  // h_new_S

  // ---- predictors ----
  float* out = (float*)d_out;
  dot_k<<<EDGE_BLOCKS, 256, 0, stream>>>(B0, item_emb, rate_src, rate_dst, out, NR);
  dot_k<<<EDGE_BLOCKS, 256, 0, stream>>>(B0, item_emb, neg_rate_src, neg_rate_dst, out + NR, NR);
  dot_k<<<EDGE_BLOCKS, 256, 0, stream>>>(B5, user_emb, link_src, link_dst, out + 2 * (size_t)NR, NL);
  dot_k<<<EDGE_BLOCKS, 256, 0, stream>>>(B5, user_emb, neg_link_src, neg_link_dst, out + 2 * (size_t)NR + NL, NL);
}

// Round 13
// 1641.972 us; speedup vs baseline: 1.5577x; 1.5577x over previous
//
#include <hip/hip_runtime.h>

// ---------------------------------------------------------------------------
// MutualRec forward: 5x GATv2 + ChebConv(k=3) + mutualistic MLP + edge dots
// R13: R10 structure, but ALL intermediate node tables stored as bf16
//   (f32 compute, round-to-nearest stores). Embeddings pre-converted to bf16
//   copies for gather/dot use. GEMM X scalar-chain reads 2 bf16 per dword
//   (halved s_loads); gathers/dots move half the bytes. W stays f32 in LDS.
// ---------------------------------------------------------------------------

#define LRELU_SLOPE 0.2f
#define GEMM_BLOCKS 2048
#define DUAL_BLOCKS 1024
#define EDGE_BLOCKS 2048

typedef unsigned short u16;
typedef unsigned int uint32;

__device__ __forceinline__ float b2f(u16 u) {
  return __uint_as_float(((uint32)u) << 16);
}
__device__ __forceinline__ u16 f2b(float f) {
  uint32 u = __float_as_uint(f);
  uint32 r = (u + 0x7fffu + ((u >> 16) & 1u)) >> 16;
  return (u16)r;
}
// two bf16 packed in a dword:
__device__ __forceinline__ float blo(uint32 p) { return __uint_as_float(p << 16); }
__device__ __forceinline__ float bhi(uint32 p) { return __uint_as_float(p & 0xffff0000u); }

// ---- f32 -> bf16 table conversion (vectorized) ----
__global__ void cvt_k(const float4* __restrict__ X, ushort4* __restrict__ Y, int n4) {
  const int stride = gridDim.x * blockDim.x;
  for (int i = blockIdx.x * blockDim.x + threadIdx.x; i < n4; i += stride) {
    const float4 v = X[i];
    ushort4 o;
    o.x = f2b(v.x); o.y = f2b(v.y); o.z = f2b(v.z); o.w = f2b(v.w);
    Y[i] = o;
  }
}

// ============================ GEMM family ==================================
// Y[N,64] = sum_m X_m[N,64] @ W[m] + b ; X bf16, W f32 [NMAT*64,64], Y bf16.
template <int NMAT>
__global__ void gemm_multi_k(const u16* __restrict__ X0, const u16* __restrict__ X1,
                             const u16* __restrict__ X2, const float* __restrict__ W,
                             const float* __restrict__ b, u16* __restrict__ Y, int N) {
  __shared__ float Ws[NMAT * 4096];
  for (int i = threadIdx.x; i < NMAT * 4096; i += 256) Ws[i] = W[i];
  __syncthreads();
  const int lane = threadIdx.x & 63;
  const int gw = (blockIdx.x * 256 + threadIdx.x) >> 6;
  const int nw = (gridDim.x * 256) >> 6;
  const float bj = b[lane];
  for (int r0 = gw * 4; r0 < N; r0 += nw * 4) {
    const int ru = __builtin_amdgcn_readfirstlane(r0);
    const int r1 = (ru + 1 < N) ? ru + 1 : ru;
    const int r2 = (ru + 2 < N) ? ru + 2 : ru;
    const int r3 = (ru + 3 < N) ? ru + 3 : ru;
    float y0 = bj, y1 = bj, y2 = bj, y3 = bj;
#pragma unroll
    for (int m = 0; m < NMAT; ++m) {
      const u16* Xm = (m == 0) ? X0 : ((m == 1) ? X1 : X2);
      const uint32* xr0 = (const uint32*)Xm + (size_t)ru * 32;
      const uint32* xr1 = (const uint32*)Xm + (size_t)r1 * 32;
      const uint32* xr2 = (const uint32*)Xm + (size_t)r2 * 32;
      const uint32* xr3 = (const uint32*)Xm + (size_t)r3 * 32;
      const float* wm = Ws + m * 4096;
#pragma unroll 1
      for (int kp = 0; kp < 32; kp += 8) {
#pragma unroll
        for (int j = 0; j < 8; ++j) {
          const uint32 p0 = xr0[kp + j], p1 = xr1[kp + j];
          const uint32 p2 = xr2[kp + j], p3 = xr3[kp + j];
          const int k = (kp + j) * 2;
          const float wl = wm[k * 64 + lane];
          const float wh = wm[(k + 1) * 64 + lane];
          y0 = fmaf(blo(p0), wl, y0); y0 = fmaf(bhi(p0), wh, y0);
          y1 = fmaf(blo(p1), wl, y1); y1 = fmaf(bhi(p1), wh, y1);
          y2 = fmaf(blo(p2), wl, y2); y2 = fmaf(bhi(p2), wh, y2);
          y3 = fmaf(blo(p3), wl, y3); y3 = fmaf(bhi(p3), wh, y3);
        }
      }
    }
    Y[(size_t)ru * 64 + lane] = f2b(y0);
    if (ru + 1 < N) Y[(size_t)(ru + 1) * 64 + lane] = f2b(y1);
    if (ru + 2 < N) Y[(size_t)(ru + 2) * 64 + lane] = f2b(y2);
    if (ru + 3 < N) Y[(size_t)(ru + 3) * 64 + lane] = f2b(y3);
  }
}

// ---- proj_k<NP>: Y_p = X @ W_p + b_p (bf16 X stream, NP<=2 outputs) ----
template <int NP>
__global__ void proj_k(const u16* __restrict__ X,
                       const float* __restrict__ W0, const float* __restrict__ W1,
                       const float* __restrict__ b0, const float* __restrict__ b1,
                       u16* __restrict__ Y0, u16* __restrict__ Y1, int N) {
  __shared__ float Ws[NP * 4096];
  for (int i = threadIdx.x; i < 4096; i += 256) Ws[i] = W0[i];
  if (NP > 1) for (int i = threadIdx.x; i < 4096; i += 256) Ws[4096 + i] = W1[i];
  __syncthreads();
  const int lane = threadIdx.x & 63;
  const int gw = (blockIdx.x * 256 + threadIdx.x) >> 6;
  const int nw = (gridDim.x * 256) >> 6;
  const float bj0 = b0[lane];
  const float bj1 = (NP > 1) ? b1[lane] : 0.0f;
  for (int r0 = gw * 4; r0 < N; r0 += nw * 4) {
    const int ru = __builtin_amdgcn_readfirstlane(r0);
    const int r1 = (ru + 1 < N) ? ru + 1 : ru;
    const int r2 = (ru + 2 < N) ? ru + 2 : ru;
    const int r3 = (ru + 3 < N) ? ru + 3 : ru;
    const uint32* xr0 = (const uint32*)X + (size_t)ru * 32;
    const uint32* xr1 = (const uint32*)X + (size_t)r1 * 32;
    const uint32* xr2 = (const uint32*)X + (size_t)r2 * 32;
    const uint32* xr3 = (const uint32*)X + (size_t)r3 * 32;
    float y0 = bj0, y1 = bj0, y2 = bj0, y3 = bj0;
    float z0 = bj1, z1 = bj1, z2 = bj1, z3 = bj1;
#pragma unroll 1
    for (int kp = 0; kp < 32; kp += 8) {
#pragma unroll
      for (int j = 0; j < 8; ++j) {
        const uint32 p0 = xr0[kp + j], p1 = xr1[kp + j];
        const uint32 p2 = xr2[kp + j], p3 = xr3[kp + j];
        const int k = (kp + j) * 2;
        const float al = Ws[k * 64 + lane];
        const float ah = Ws[(k + 1) * 64 + lane];
        y0 = fmaf(blo(p0), al, y0); y0 = fmaf(bhi(p0), ah, y0);
        y1 = fmaf(blo(p1), al, y1); y1 = fmaf(bhi(p1), ah, y1);
        y2 = fmaf(blo(p2), al, y2); y2 = fmaf(bhi(p2), ah, y2);
        y3 = fmaf(blo(p3), al, y3); y3 = fmaf(bhi(p3), ah, y3);
        if (NP > 1) {
          const float bl2 = Ws[4096 + k * 64 + lane];
          const float bh2 = Ws[4096 + (k + 1) * 64 + lane];
          z0 = fmaf(blo(p0), bl2, z0); z0 = fmaf(bhi(p0), bh2, z0);
          z1 = fmaf(blo(p1), bl2, z1); z1 = fmaf(bhi(p1), bh2, z1);
          z2 = fmaf(blo(p2), bl2, z2); z2 = fmaf(bhi(p2), bh2, z2);
          z3 = fmaf(blo(p3), bl2, z3); z3 = fmaf(bhi(p3), bh2, z3);
        }
      }
    }
    Y0[(size_t)ru * 64 + lane] = f2b(y0);
    if (NP > 1) Y1[(size_t)ru * 64 + lane] = f2b(z0);
    if (ru + 1 < N) {
      Y0[(size_t)(ru + 1) * 64 + lane] = f2b(y1);
      if (NP > 1) Y1[(size_t)(ru + 1) * 64 + lane] = f2b(z1);
    }
    if (ru + 2 < N) {
      Y0[(size_t)(ru + 2) * 64 + lane] = f2b(y2);
      if (NP > 1) Y1[(size_t)(ru + 2) * 64 + lane] = f2b(z2);
    }
    if (ru + 3 < N) {
      Y0[(size_t)(ru + 3) * 64 + lane] = f2b(y3);
      if (NP > 1) Y1[(size_t)(ru + 3) * 64 + lane] = f2b(z3);
    }
  }
}

// ---- dual128_k<SHARED>: Y0=[A0,C0]@W0+b0 ; Y1=[A1,C1]@W1+b1 (bf16 I/O) ----
template <bool SHARED>
__global__ void dual128_k(const u16* __restrict__ A0, const u16* __restrict__ C0,
                          const u16* __restrict__ A1, const u16* __restrict__ C1,
                          const float* __restrict__ W0, const float* __restrict__ W1,
                          const float* __restrict__ b0, const float* __restrict__ b1,
                          u16* __restrict__ Y0, u16* __restrict__ Y1, int N) {
  __shared__ float Ws[2 * 8192];
  for (int i = threadIdx.x; i < 8192; i += 256) Ws[i] = W0[i];
  for (int i = threadIdx.x; i < 8192; i += 256) Ws[8192 + i] = W1[i];
  __syncthreads();
  const int lane = threadIdx.x & 63;
  const int gw = (blockIdx.x * 256 + threadIdx.x) >> 6;
  const int nw = (gridDim.x * 256) >> 6;
  const float bj0 = b0[lane], bj1 = b1[lane];
  for (int r0 = gw * 4; r0 < N; r0 += nw * 4) {
    const int ru = __builtin_amdgcn_readfirstlane(r0);
    const int r1 = (ru + 1 < N) ? ru + 1 : ru;
    const int r2 = (ru + 2 < N) ? ru + 2 : ru;
    const int r3 = (ru + 3 < N) ? ru + 3 : ru;
    float ya0 = bj0, ya1 = bj0, ya2 = bj0, ya3 = bj0;
    float yb0 = bj1, yb1 = bj1, yb2 = bj1, yb3 = bj1;
    // phase A0 -> ya (W0 rows 0..63)
    {
      const uint32* xr0 = (const uint32*)A0 + (size_t)ru * 32;
      const uint32* xr1 = (const uint32*)A0 + (size_t)r1 * 32;
      const uint32* xr2 = (const uint32*)A0 + (size_t)r2 * 32;
      const uint32* xr3 = (const uint32*)A0 + (size_t)r3 * 32;
#pragma unroll 1
      for (int kp = 0; kp < 32; kp += 8) {
#pragma unroll
        for (int j = 0; j < 8; ++j) {
          const uint32 p0 = xr0[kp + j], p1 = xr1[kp + j];
          const uint32 p2 = xr2[kp + j], p3 = xr3[kp + j];
          const int k = (kp + j) * 2;
          const float wl = Ws[k * 64 + lane], wh = Ws[(k + 1) * 64 + lane];
          ya0 = fmaf(blo(p0), wl, ya0); ya0 = fmaf(bhi(p0), wh, ya0);
          ya1 = fmaf(blo(p1), wl, ya1); ya1 = fmaf(bhi(p1), wh, ya1);
          ya2 = fmaf(blo(p2), wl, ya2); ya2 = fmaf(bhi(p2), wh, ya2);
          ya3 = fmaf(blo(p3), wl, ya3); ya3 = fmaf(bhi(p3), wh, ya3);
        }
      }
    }
    // phase A1 -> yb (W1 rows 0..63)
    {
      const uint32* xr0 = (const uint32*)A1 + (size_t)ru * 32;
      const uint32* xr1 = (const uint32*)A1 + (size_t)r1 * 32;
      const uint32* xr2 = (const uint32*)A1 + (size_t)r2 * 32;
      const uint32* xr3 = (const uint32*)A1 + (size_t)r3 * 32;
#pragma unroll 1
      for (int kp = 0; kp < 32; kp += 8) {
#pragma unroll
        for (int j = 0; j < 8; ++j) {
          const uint32 p0 = xr0[kp + j], p1 = xr1[kp + j];
          const uint32 p2 = xr2[kp + j], p3 = xr3[kp + j];
          const int k = (kp + j) * 2;
          const float wl = Ws[8192 + k * 64 + lane], wh = Ws[8192 + (k + 1) * 64 + lane];
          yb0 = fmaf(blo(p0), wl, yb0); yb0 = fmaf(bhi(p0), wh, yb0);
          yb1 = fmaf(blo(p1), wl, yb1); yb1 = fmaf(bhi(p1), wh, yb1);
          yb2 = fmaf(blo(p2), wl, yb2); yb2 = fmaf(bhi(p2), wh, yb2);
          yb3 = fmaf(blo(p3), wl, yb3); yb3 = fmaf(bhi(p3), wh, yb3);
        }
      }
    }
    if (SHARED) {
      const uint32* xr0 = (const uint32*)C0 + (size_t)ru * 32;
      const uint32* xr1 = (const uint32*)C0 + (size_t)r1 * 32;
      const uint32* xr2 = (const uint32*)C0 + (size_t)r2 * 32;
      const uint32* xr3 = (const uint32*)C0 + (size_t)r3 * 32;
#pragma unroll 1
      for (int kp = 0; kp < 32; kp += 8) {
#pragma unroll
        for (int j = 0; j < 8; ++j) {
          const uint32 p0 = xr0[kp + j], p1 = xr1[kp + j];
          const uint32 p2 = xr2[kp + j], p3 = xr3[kp + j];
          const int k = 64 + (kp + j) * 2;
          const float al = Ws[k * 64 + lane], ah = Ws[(k + 1) * 64 + lane];
          const float bl2 = Ws[8192 + k * 64 + lane], bh2 = Ws[8192 + (k + 1) * 64 + lane];
          ya0 = fmaf(blo(p0), al, ya0); ya0 = fmaf(bhi(p0), ah, ya0);
          yb0 = fmaf(blo(p0), bl2, yb0); yb0 = fmaf(bhi(p0), bh2, yb0);
          ya1 = fmaf(blo(p1), al, ya1); ya1 = fmaf(bhi(p1), ah, ya1);
          yb1 = fmaf(blo(p1), bl2, yb1); yb1 = fmaf(bhi(p1), bh2, yb1);
          ya2 = fmaf(blo(p2), al, ya2); ya2 = fmaf(bhi(p2), ah, ya2);
          yb2 = fmaf(blo(p2), bl2, yb2); yb2 = fmaf(bhi(p2), bh2, yb2);
          ya3 = fmaf(blo(p3), al, ya3); ya3 = fmaf(bhi(p3), ah, ya3);
          yb3 = fmaf(blo(p3), bl2, yb3); yb3 = fmaf(bhi(p3), bh2, yb3);
        }
      }
    } else {
      {
        const uint32* xr0 = (const uint32*)C0 + (size_t)ru * 32;
        const uint32* xr1 = (const uint32*)C0 + (size_t)r1 * 32;
        const uint32* xr2 = (const uint32*)C0 + (size_t)r2 * 32;
        const uint32* xr3 = (const uint32*)C0 + (size_t)r3 * 32;
#pragma unroll 1
        for (int kp = 0; kp < 32; kp += 8) {
#pragma unroll
          for (int j = 0; j < 8; ++j) {
            const uint32 p0 = xr0[kp + j], p1 = xr1[kp + j];
            const uint32 p2 = xr2[kp + j], p3 = xr3[kp + j];
            const int k = 64 + (kp + j) * 2;
            const float wl = Ws[k * 64 + lane], wh = Ws[(k + 1) * 64 + lane];
            ya0 = fmaf(blo(p0), wl, ya0); ya0 = fmaf(bhi(p0), wh, ya0);
            ya1 = fmaf(blo(p1), wl, ya1); ya1 = fmaf(bhi(p1), wh, ya1);
            ya2 = fmaf(blo(p2), wl, ya2); ya2 = fmaf(bhi(p2), wh, ya2);
            ya3 = fmaf(blo(p3), wl, ya3); ya3 = fmaf(bhi(p3), wh, ya3);
          }
        }
      }
      {
        const uint32* xr0 = (const uint32*)C1 + (size_t)ru * 32;
        const uint32* xr1 = (const uint32*)C1 + (size_t)r1 * 32;
        const uint32* xr2 = (const uint32*)C1 + (size_t)r2 * 32;
        const uint32* xr3 = (const uint32*)C1 + (size_t)r3 * 32;
#pragma unroll 1
        for (int kp = 0; kp < 32; kp += 8) {
#pragma unroll
          for (int j = 0; j < 8; ++j) {
            const uint32 p0 = xr0[kp + j], p1 = xr1[kp + j];
            const uint32 p2 = xr2[kp + j], p3 = xr3[kp + j];
            const int k = 64 + (kp + j) * 2;
            const float wl = Ws[8192 + k * 64 + lane], wh = Ws[8192 + (k + 1) * 64 + lane];
            yb0 = fmaf(blo(p0), wl, yb0); yb0 = fmaf(bhi(p0), wh, yb0);
            yb1 = fmaf(blo(p1), wl, yb1); yb1 = fmaf(bhi(p1), wh, yb1);
            yb2 = fmaf(blo(p2), wl, yb2); yb2 = fmaf(bhi(p2), wh, yb2);
            yb3 = fmaf(blo(p3), wl, yb3); yb3 = fmaf(bhi(p3), wh, yb3);
          }
        }
      }
    }
    Y0[(size_t)ru * 64 + lane] = f2b(ya0);
    Y1[(size_t)ru * 64 + lane] = f2b(yb0);
    if (ru + 1 < N) { Y0[(size_t)(ru + 1) * 64 + lane] = f2b(ya1); Y1[(size_t)(ru + 1) * 64 + lane] = f2b(yb1); }
    if (ru + 2 < N) { Y0[(size_t)(ru + 2) * 64 + lane] = f2b(ya2); Y1[(size_t)(ru + 2) * 64 + lane] = f2b(yb2); }
    if (ru + 3 < N) { Y0[(size_t)(ru + 3) * 64 + lane] = f2b(ya3); Y1[(size_t)(ru + 3) * 64 + lane] = f2b(yb3); }
  }
}

// ========================= CSR build (counting sort) =======================
__global__ void hist_k(const int* __restrict__ key, int* __restrict__ cnt, int E) {
  const int e = blockIdx.x * blockDim.x + threadIdx.x;
  if (e < E) atomicAdd(cnt + key[e], 1);
}

__global__ void scan1_k(const int* __restrict__ in, int* __restrict__ out,
                        int* __restrict__ bsum, int n) {
  __shared__ int tmp[256];
  const int t = threadIdx.x;
  const int base = blockIdx.x * 1024 + t * 4;
  int v0 = (base + 0 < n) ? in[base + 0] : 0;
  int v1 = (base + 1 < n) ? in[base + 1] : 0;
  int v2 = (base + 2 < n) ? in[base + 2] : 0;
  int v3 = (base + 3 < n) ? in[base + 3] : 0;
  const int s = v0 + v1 + v2 + v3;
  tmp[t] = s;
  __syncthreads();
  for (int off = 1; off < 256; off <<= 1) {
    const int x = (t >= off) ? tmp[t - off] : 0;
    __syncthreads();
    tmp[t] += x;
    __syncthreads();
  }
  const int excl = tmp[t] - s;
  if (t == 255) bsum[blockIdx.x] = tmp[255];
  if (base + 0 < n) out[base + 0] = excl;
  if (base + 1 < n) out[base + 1] = excl + v0;
  if (base + 2 < n) out[base + 2] = excl + v0 + v1;
  if (base + 3 < n) out[base + 3] = excl + v0 + v1 + v2;
}
__global__ void scan2_k(int* __restrict__ bsum, int nb) {
  if (threadIdx.x == 0) {
    int acc = 0;
    for (int i = 0; i < nb; ++i) { const int v = bsum[i]; bsum[i] = acc; acc += v; }
  }
}
__global__ void scan3_k(int* __restrict__ out, const int* __restrict__ bsum, int n) {
  const int i = blockIdx.x * blockDim.x + threadIdx.x;
  if (i < n) out[i] += bsum[i >> 10];
}

__global__ void scatter_k(const int* __restrict__ key, const int* __restrict__ other,
                          int* __restrict__ cursor, int* __restrict__ srt, int E) {
  const int e = blockIdx.x * blockDim.x + threadIdx.x;
  if (e < E) {
    const int p = atomicAdd(cursor + key[e], 1);
    srt[p] = other[e];
  }
}

// ======================= CSR-based graph kernels (bf16) ====================
__global__ void gat_csr_k(const u16* __restrict__ fs, const u16* __restrict__ fd,
                          const float* __restrict__ attn,
                          const int* __restrict__ rowptr, const int* __restrict__ nbr,
                          u16* __restrict__ out, int N) {
  const int lane = threadIdx.x & 63;
  const int wid = (blockIdx.x * blockDim.x + threadIdx.x) >> 6;
  const int nw = (gridDim.x * blockDim.x) >> 6;
  const float aw = attn[lane];
  for (int n = wid; n < N; n += nw) {
    const int beg = rowptr[n], end = rowptr[n + 1];
    const float fdv = b2f(fd[(size_t)n * 64 + lane]);
    float acc = 0.0f, den = 0.0f;
    int e = beg;
    for (; e + 1 < end; e += 2) {
      const int s0 = nbr[e], s1 = nbr[e + 1];
      const float f0 = b2f(fs[(size_t)s0 * 64 + lane]);
      const float f1 = b2f(fs[(size_t)s1 * 64 + lane]);
      float v0 = f0 + fdv; v0 = v0 > 0.0f ? v0 : LRELU_SLOPE * v0;
      float v1 = f1 + fdv; v1 = v1 > 0.0f ? v1 : LRELU_SLOPE * v1;
      float p0 = v0 * aw, p1 = v1 * aw;
#pragma unroll
      for (int o = 32; o; o >>= 1) {
        p0 += __shfl_xor(p0, o, 64);
        p1 += __shfl_xor(p1, o, 64);
      }
      const float e0 = __expf(p0), e1 = __expf(p1);
      den += e0 + e1;
      acc = fmaf(e0, f0, acc);
      acc = fmaf(e1, f1, acc);
    }
    if (e < end) {
      const int s0 = nbr[e];
      const float f0 = b2f(fs[(size_t)s0 * 64 + lane]);
      float v0 = f0 + fdv; v0 = v0 > 0.0f ? v0 : LRELU_SLOPE * v0;
      float p0 = v0 * aw;
#pragma unroll
      for (int o = 32; o; o >>= 1) p0 += __shfl_xor(p0, o, 64);
      const float e0 = __expf(p0);
      den += e0;
      acc = fmaf(e0, f0, acc);
    }
    const float inv = den > 0.0f ? 1.0f / den : 0.0f;
    out[(size_t)n * 64 + lane] = f2b(acc * inv);
  }
}

// Fused Cheb step (MODE 1: T1; MODE 2: T2); bf16 tables, f32 math.
template <int MODE>
__global__ void cheb_csr_k(const u16* __restrict__ x, const u16* __restrict__ T0,
                           const u16* __restrict__ Tp, const float* __restrict__ dinv,
                           const float* __restrict__ lam,
                           const int* __restrict__ rowptr, const int* __restrict__ nbr,
                           u16* __restrict__ outT, int N) {
  const float re = 2.0f / lam[0];
  const int lane = threadIdx.x & 63;
  const int wid = (blockIdx.x * blockDim.x + threadIdx.x) >> 6;
  const int nw = (gridDim.x * blockDim.x) >> 6;
  for (int n = wid; n < N; n += nw) {
    const int beg = rowptr[n], end = rowptr[n + 1];
    float acc = 0.0f;
    int e = beg;
    for (; e + 1 < end; e += 2) {
      const int s0 = nbr[e], s1 = nbr[e + 1];
      acc = fmaf(b2f(x[(size_t)s0 * 64 + lane]), dinv[s0], acc);
      acc = fmaf(b2f(x[(size_t)s1 * 64 + lane]), dinv[s1], acc);
    }
    if (e < end) {
      const int s0 = nbr[e];
      acc = fmaf(b2f(x[(size_t)s0 * 64 + lane]), dinv[s0], acc);
    }
    const float hv = acc * dinv[n];
    float r;
    if (MODE == 1) {
      r = -re * hv + (re - 1.0f) * b2f(T0[(size_t)n * 64 + lane]);
    } else {
      r = -2.0f * re * hv + 2.0f * (re - 1.0f) * b2f(Tp[(size_t)n * 64 + lane])
          - b2f(T0[(size_t)n * 64 + lane]);
    }
    outT[(size_t)n * 64 + lane] = f2b(r);
  }
}

__global__ void dinv_k(const int* __restrict__ rowptr, float* __restrict__ dinv, int N) {
  const int i = blockIdx.x * blockDim.x + threadIdx.x;
  if (i < N) {
    const float deg = (float)(rowptr[i + 1] - rowptr[i]);
    dinv[i] = rsqrtf(fmaxf(deg, 1.0f));
  }
}

// ---- mutualistic (bf16 I/O) ----
__global__ void mut_k(const u16* __restrict__ hP, const u16* __restrict__ hS,
                      u16* __restrict__ mP, u16* __restrict__ mS, int N) {
  const int lane = threadIdx.x & 63;
  const int u = (blockIdx.x * blockDim.x + threadIdx.x) >> 6;
  if (u >= N) return;
  const float p = b2f(hP[(size_t)u * 64 + lane]);
  const float s = b2f(hS[(size_t)u * 64 + lane]);
  const float m = p * s;
  float mxp = p, mxs = s;
#pragma unroll
  for (int o = 32; o; o >>= 1) {
    mxp = fmaxf(mxp, __shfl_xor(mxp, o, 64));
    mxs = fmaxf(mxs, __shfl_xor(mxs, o, 64));
  }
  const float ep = __expf(p - mxp);
  const float es = __expf(s - mxs);
  float sp = ep, ss = es;
#pragma unroll
  for (int o = 32; o; o >>= 1) {
    sp += __shfl_xor(sp, o, 64);
    ss += __shfl_xor(ss, o, 64);
  }
  mP[(size_t)u * 64 + lane] = f2b(m * (ep / sp));
  mS[(size_t)u * 64 + lane] = f2b(m * (es / ss));
}

// ---- edge dot (bf16 tables, f32 out; ILP-2) ----
__global__ void dot_k(const u16* __restrict__ A, const u16* __restrict__ Bm,
                      const int* __restrict__ src, const int* __restrict__ dst,
                      float* __restrict__ out, int E) {
  const int lane = threadIdx.x & 63;
  const int wid = (blockIdx.x * blockDim.x + threadIdx.x) >> 6;
  const int nw = (gridDim.x * blockDim.x) >> 6;
  for (int e0 = wid * 2; e0 < E; e0 += nw * 2) {
    const bool has1 = (e0 + 1 < E);
    const int s0 = src[e0], d0 = dst[e0];
    const int s1 = has1 ? src[e0 + 1] : s0;
    const int d1 = has1 ? dst[e0 + 1] : d0;
    float p0 = b2f(A[(size_t)s0 * 64 + lane]) * b2f(Bm[(size_t)d0 * 64 + lane]);
    float p1 = b2f(A[(size_t)s1 * 64 + lane]) * b2f(Bm[(size_t)d1 * 64 + lane]);
#pragma unroll
    for (int o = 32; o; o >>= 1) {
      p0 += __shfl_xor(p0, o, 64);
      p1 += __shfl_xor(p1, o, 64);
    }
    if (lane == 0) {
      out[e0] = p0;
      if (has1) out[e0 + 1] = p1;
    }
  }
}

// ---------------------------------------------------------------------------

static void build_csr(const int* key, const int* other, int E, int N,
                      int* rowptr, int* srt, int* cursor, int* bsum,
                      hipStream_t stream) {
  const int n1 = N + 1;
  hipMemsetAsync(cursor, 0, (size_t)n1 * 4, stream);
  hist_k<<<(E + 255) / 256, 256, 0, stream>>>(key, cursor, E);
  const int nb = (n1 + 1023) / 1024;
  scan1_k<<<nb, 256, 0, stream>>>(cursor, rowptr, bsum, n1);
  scan2_k<<<1, 64, 0, stream>>>(bsum, nb);
  scan3_k<<<(n1 + 255) / 256, 256, 0, stream>>>(rowptr, bsum, n1);
  hipMemcpyAsync(cursor, rowptr, (size_t)N * 4, hipMemcpyDeviceToDevice, stream);
  scatter_k<<<(E + 255) / 256, 256, 0, stream>>>(key, other, cursor, srt, E);
}

extern "C" void kernel_launch(void* const* d_in, const int* in_sizes, int n_in,
                              void* d_out, int out_size, void* d_ws, size_t ws_size,
                              hipStream_t stream) {
  const float* user_emb = (const float*)d_in[0];
  const float* item_emb = (const float*)d_in[1];
  const int* rate_src = (const int*)d_in[2];
  const int* rate_dst = (const int*)d_in[3];
  const int* link_src = (const int*)d_in[4];
  const int* link_dst = (const int*)d_in[5];
  const int* neg_rate_src = (const int*)d_in[6];
  const int* neg_rate_dst = (const int*)d_in[7];
  const int* neg_link_src = (const int*)d_in[8];
  const int* neg_link_dst = (const int*)d_in[9];
  const float* lam = (const float*)d_in[10];
  const float* gat_Wsrc = (const float*)d_in[11];
  const float* gat_bsrc = (const float*)d_in[12];
  const float* gat_Wdst = (const float*)d_in[13];
  const float* gat_bdst = (const float*)d_in[14];
  const float* gat_attn = (const float*)d_in[15];
  const float* W_out = (const float*)d_in[16];
  const float* b_out = (const float*)d_in[17];
  const float* cheb_W = (const float*)d_in[18];
  const float* cheb_b = (const float*)d_in[19];
  const float* Wc = (const float*)d_in[20];
  const float* bc = (const float*)d_in[21];
  const float* Wsm = (const float*)d_in[22];
  const float* bs = (const float*)d_in[23];
  const float* WpP = (const float*)d_in[24];
  const float* bpP = (const float*)d_in[25];
  const float* WpS = (const float*)d_in[26];
  const float* bpS = (const float*)d_in[27];

  const int NU = in_sizes[0] / 64;
  const int NI = in_sizes[1] / 64;
  const int NR = in_sizes[2];
  const int NL = in_sizes[4];
  const int NMAX = NU > NI ? NU : NI;
  const size_t MAT = (size_t)NMAX * 64;

  u16* ub = (u16*)d_ws;                       // user_emb bf16 copy
  u16* ib = ub + (size_t)NU * 64;             // item_emb bf16 copy
  u16* B0 = ib + (size_t)NI * 64;
  u16* B1 = B0 + MAT;
  u16* B2 = B1 + MAT;
  u16* B3 = B2 + MAT;
  u16* B4 = B3 + MAT;
  u16* B5 = B4 + MAT;
  u16* B6 = B5 + MAT;
  u16* B7 = B6 + MAT;
  int* ip = (int*)(B7 + MAT);
  int* rp_rd = ip;                   // NI+1
  int* rp_rs = rp_rd + (NI + 1);     // NU+1
  int* rp_ld = rp_rs + (NU + 1);     // NU+1
  int* srt_rd = rp_ld + (NU + 1);    // NR
  int* srt_rs = srt_rd + NR;         // NR
  int* srt_ld = srt_rs + NR;         // NL
  int* cursor = srt_ld + NL;         // NMAX+1
  int* bsum = cursor + (NMAX + 1);   // 256
  float* dinv = (float*)(bsum + 256);  // NU

  const int W64 = 64 * 64, B64 = 64;

  // ---- bf16 copies of embeddings ----
  cvt_k<<<1024, 256, 0, stream>>>((const float4*)user_emb, (ushort4*)ub, NU * 16);
  cvt_k<<<1024, 256, 0, stream>>>((const float4*)item_emb, (ushort4*)ib, NI * 16);

  // ---- 3 CSR groupings ----
  build_csr(rate_dst, rate_src, NR, NI, rp_rd, srt_rd, cursor, bsum, stream);
  build_csr(rate_src, rate_dst, NR, NU, rp_rs, srt_rs, cursor, bsum, stream);
  build_csr(link_dst, link_src, NL, NU, rp_ld, srt_ld, cursor, bsum, stream);

  // ---- user projections: fs0->B0, fd1->B1 ; fd2->B2, fd3->B3 ----
  proj_k<2><<<GEMM_BLOCKS, 256, 0, stream>>>(
      ub, gat_Wsrc + 0 * W64, gat_Wdst + 1 * W64,
      gat_bsrc + 0 * B64, gat_bdst + 1 * B64, B0, B1, NU);
  proj_k<2><<<GEMM_BLOCKS, 256, 0, stream>>>(
      ub, gat_Wdst + 2 * W64, gat_Wdst + 3 * W64,
      gat_bdst + 2 * B64, gat_bdst + 3 * B64, B2, B3, NU);
  // ---- item projections: fd0->B4, fs1->B5 ----
  proj_k<2><<<GEMM_BLOCKS, 256, 0, stream>>>(
      ib, gat_Wdst + 0 * W64, gat_Wsrc + 1 * W64,
      gat_bdst + 0 * B64, gat_bsrc + 1 * B64, B4, B5, NI);

  // ---- gat0: (fs=B0, fd=B4) over rate-by-item -> B6 (h1_item) ----
  gat_csr_k<<<EDGE_BLOCKS, 256, 0, stream>>>(B0, B4, gat_attn + 0 * B64, rp_rd, srt_rd, B6, NI);
  // ---- gat1: (fs=B5, fd=B1) over rate-by-user -> B7 (h2_user) ----
  gat_csr_k<<<EDGE_BLOCKS, 256, 0, stream>>>(B5, B1, gat_attn + 1 * B64, rp_rs, srt_rs, B7, NU);

  // ---- fs2 = h1_item @ Ws2 -> B0 ; gat2 (fs=B0, fd=B2) -> B4 (item_infl) ----
  proj_k<1><<<GEMM_BLOCKS, 256, 0, stream>>>(
      B6, gat_Wsrc + 2 * W64, nullptr, gat_bsrc + 2 * B64, nullptr, B0, nullptr, NI);
  gat_csr_k<<<EDGE_BLOCKS, 256, 0, stream>>>(B0, B2, gat_attn + 2 * B64, rp_rs, srt_rs, B4, NU);

  // ---- fs3 = h2_user @ Ws3 -> B5 ; gat3 (fs=B5, fd=B3) -> B2 (social_item) ----
  proj_k<1><<<GEMM_BLOCKS, 256, 0, stream>>>(
      B7, gat_Wsrc + 3 * W64, nullptr, gat_bsrc + 3 * B64, nullptr, B5, nullptr, NU);
  gat_csr_k<<<EDGE_BLOCKS, 256, 0, stream>>>(B5, B3, gat_attn + 3 * B64, rp_ld, srt_ld, B2, NU);

  // ---- user_pref = [item_infl(B4), social_item(B2)] @ W_out + b_out -> B0 ----
  gemm_multi_k<2><<<GEMM_BLOCKS, 256, 0, stream>>>(B4, B2, nullptr, W_out, b_out, B0, NU);

  // ---- ChebConv(k=3): T1->B5, T2->B3, rst->B6 ----
  dinv_k<<<(NU + 255) / 256, 256, 0, stream>>>(rp_ld, dinv, NU);
  cheb_csr_k<1><<<EDGE_BLOCKS, 256, 0, stream>>>(ub, ub, nullptr, dinv, lam,
                                                 rp_ld, srt_ld, B5, NU);
  cheb_csr_k<2><<<EDGE_BLOCKS, 256, 0, stream>>>(B5, ub, B5, dinv, lam,
                                                 rp_ld, srt_ld, B3, NU);
  gemm_multi_k<3><<<GEMM_BLOCKS, 256, 0, stream>>>(ub, B5, B3, cheb_W, cheb_b, B6, NU);

  // ---- rst projections: fs4->B4, fd4->B2 ; gat4 -> B5 (user_social) ----
  proj_k<2><<<GEMM_BLOCKS, 256, 0, stream>>>(
      B6, gat_Wsrc + 4 * W64, gat_Wdst + 4 * W64,
      gat_bsrc + 4 * B64, gat_bdst + 4 * B64, B4, B2, NU);
  gat_csr_k<<<EDGE_BLOCKS, 256, 0, stream>>>(B4, B2, gat_attn + 4 * B64, rp_ld, srt_ld, B5, NU);

  // ---- mutualistic: h_uP->B4, h_uS->B2 (shared ub read) ----
  dual128_k<true><<<DUAL_BLOCKS, 256, 0, stream>>>(
      B0, ub, B5, nullptr, Wc, Wsm, bc, bs, B4, B2, NU);
  mut_k<<<(NU + 3) / 4, 256, 0, stream>>>(B4, B2, B3, B7, NU);  // mP->B3, mS->B7
  // h_new_P->B0, h_new_S->B5
  dual128_k<false><<<DUAL_BLOCKS, 256, 0, stream>>>(
      B3, B4, B7, B2, WpP, WpS, bpP, bpS, B0, B5, NU);

  // ---- predictors ----
  float* out = (float*)d_out;
  dot_k<<<EDGE_BLOCKS, 256, 0, stream>>>(B0, ib, rate_src, rate_dst, out, NR);
  dot_k<<<EDGE_BLOCKS, 256, 0, stream>>>(B0, ib, neg_rate_src, neg_rate_dst, out + NR, NR);
  dot_k<<<EDGE_BLOCKS, 256, 0, stream>>>(B5, ub, link_src, link_dst, out + 2 * (size_t)NR, NL);
  dot_k<<<EDGE_BLOCKS, 256, 0, stream>>>(B5, ub, neg_link_src, neg_link_dst, out + 2 * (size_t)NR + NL, NL);
}

// Round 14
// 1290.263 us; speedup vs baseline: 1.9823x; 1.2726x over previous
//
#include <hip/hip_runtime.h>

// ---------------------------------------------------------------------------
// MutualRec forward: 5x GATv2 + ChebConv(k=3) + mutualistic MLP + edge dots
// R14: bf16 rows are 128B = 32 lanes x 1 dword -> all edge kernels use
//   32-lane sub-waves (2 edges/nodes per wave), packed 2-elem math, 5-step
//   shfl reduces, ILP-2/4. GEMM family (bf16 scalar-chain) from R13.
// ---------------------------------------------------------------------------

#define LRELU_SLOPE 0.2f
#define GEMM_BLOCKS 2048
#define DUAL_BLOCKS 1024
#define EDGE_BLOCKS 2048

typedef unsigned short u16;
typedef unsigned int uint32;

__device__ __forceinline__ float b2f(u16 u) {
  return __uint_as_float(((uint32)u) << 16);
}
__device__ __forceinline__ u16 f2b(float f) {
  uint32 u = __float_as_uint(f);
  uint32 r = (u + 0x7fffu + ((u >> 16) & 1u)) >> 16;
  return (u16)r;
}
__device__ __forceinline__ float blo(uint32 p) { return __uint_as_float(p << 16); }
__device__ __forceinline__ float bhi(uint32 p) { return __uint_as_float(p & 0xffff0000u); }
__device__ __forceinline__ uint32 packb(float lo, float hi) {
  return (uint32)f2b(lo) | ((uint32)f2b(hi) << 16);
}

// ---- f32 -> bf16 table conversion (vectorized) ----
__global__ void cvt_k(const float4* __restrict__ X, ushort4* __restrict__ Y, int n4) {
  const int stride = gridDim.x * blockDim.x;
  for (int i = blockIdx.x * blockDim.x + threadIdx.x; i < n4; i += stride) {
    const float4 v = X[i];
    ushort4 o;
    o.x = f2b(v.x); o.y = f2b(v.y); o.z = f2b(v.z); o.w = f2b(v.w);
    Y[i] = o;
  }
}

// ============================ GEMM family ==================================
// Y[N,64] = sum_m X_m[N,64] @ W[m] + b ; X bf16, W f32 [NMAT*64,64], Y bf16.
template <int NMAT>
__global__ void gemm_multi_k(const u16* __restrict__ X0, const u16* __restrict__ X1,
                             const u16* __restrict__ X2, const float* __restrict__ W,
                             const float* __restrict__ b, u16* __restrict__ Y, int N) {
  __shared__ float Ws[NMAT * 4096];
  for (int i = threadIdx.x; i < NMAT * 4096; i += 256) Ws[i] = W[i];
  __syncthreads();
  const int lane = threadIdx.x & 63;
  const int gw = (blockIdx.x * 256 + threadIdx.x) >> 6;
  const int nw = (gridDim.x * 256) >> 6;
  const float bj = b[lane];
  for (int r0 = gw * 4; r0 < N; r0 += nw * 4) {
    const int ru = __builtin_amdgcn_readfirstlane(r0);
    const int r1 = (ru + 1 < N) ? ru + 1 : ru;
    const int r2 = (ru + 2 < N) ? ru + 2 : ru;
    const int r3 = (ru + 3 < N) ? ru + 3 : ru;
    float y0 = bj, y1 = bj, y2 = bj, y3 = bj;
#pragma unroll
    for (int m = 0; m < NMAT; ++m) {
      const u16* Xm = (m == 0) ? X0 : ((m == 1) ? X1 : X2);
      const uint32* xr0 = (const uint32*)Xm + (size_t)ru * 32;
      const uint32* xr1 = (const uint32*)Xm + (size_t)r1 * 32;
      const uint32* xr2 = (const uint32*)Xm + (size_t)r2 * 32;
      const uint32* xr3 = (const uint32*)Xm + (size_t)r3 * 32;
      const float* wm = Ws + m * 4096;
#pragma unroll 1
      for (int kp = 0; kp < 32; kp += 8) {
#pragma unroll
        for (int j = 0; j < 8; ++j) {
          const uint32 p0 = xr0[kp + j], p1 = xr1[kp + j];
          const uint32 p2 = xr2[kp + j], p3 = xr3[kp + j];
          const int k = (kp + j) * 2;
          const float wl = wm[k * 64 + lane];
          const float wh = wm[(k + 1) * 64 + lane];
          y0 = fmaf(blo(p0), wl, y0); y0 = fmaf(bhi(p0), wh, y0);
          y1 = fmaf(blo(p1), wl, y1); y1 = fmaf(bhi(p1), wh, y1);
          y2 = fmaf(blo(p2), wl, y2); y2 = fmaf(bhi(p2), wh, y2);
          y3 = fmaf(blo(p3), wl, y3); y3 = fmaf(bhi(p3), wh, y3);
        }
      }
    }
    Y[(size_t)ru * 64 + lane] = f2b(y0);
    if (ru + 1 < N) Y[(size_t)(ru + 1) * 64 + lane] = f2b(y1);
    if (ru + 2 < N) Y[(size_t)(ru + 2) * 64 + lane] = f2b(y2);
    if (ru + 3 < N) Y[(size_t)(ru + 3) * 64 + lane] = f2b(y3);
  }
}

// ---- proj_k<NP>: Y_p = X @ W_p + b_p (bf16 X stream, NP<=2 outputs) ----
template <int NP>
__global__ void proj_k(const u16* __restrict__ X,
                       const float* __restrict__ W0, const float* __restrict__ W1,
                       const float* __restrict__ b0, const float* __restrict__ b1,
                       u16* __restrict__ Y0, u16* __restrict__ Y1, int N) {
  __shared__ float Ws[NP * 4096];
  for (int i = threadIdx.x; i < 4096; i += 256) Ws[i] = W0[i];
  if (NP > 1) for (int i = threadIdx.x; i < 4096; i += 256) Ws[4096 + i] = W1[i];
  __syncthreads();
  const int lane = threadIdx.x & 63;
  const int gw = (blockIdx.x * 256 + threadIdx.x) >> 6;
  const int nw = (gridDim.x * 256) >> 6;
  const float bj0 = b0[lane];
  const float bj1 = (NP > 1) ? b1[lane] : 0.0f;
  for (int r0 = gw * 4; r0 < N; r0 += nw * 4) {
    const int ru = __builtin_amdgcn_readfirstlane(r0);
    const int r1 = (ru + 1 < N) ? ru + 1 : ru;
    const int r2 = (ru + 2 < N) ? ru + 2 : ru;
    const int r3 = (ru + 3 < N) ? ru + 3 : ru;
    const uint32* xr0 = (const uint32*)X + (size_t)ru * 32;
    const uint32* xr1 = (const uint32*)X + (size_t)r1 * 32;
    const uint32* xr2 = (const uint32*)X + (size_t)r2 * 32;
    const uint32* xr3 = (const uint32*)X + (size_t)r3 * 32;
    float y0 = bj0, y1 = bj0, y2 = bj0, y3 = bj0;
    float z0 = bj1, z1 = bj1, z2 = bj1, z3 = bj1;
#pragma unroll 1
    for (int kp = 0; kp < 32; kp += 8) {
#pragma unroll
      for (int j = 0; j < 8; ++j) {
        const uint32 p0 = xr0[kp + j], p1 = xr1[kp + j];
        const uint32 p2 = xr2[kp + j], p3 = xr3[kp + j];
        const int k = (kp + j) * 2;
        const float al = Ws[k * 64 + lane];
        const float ah = Ws[(k + 1) * 64 + lane];
        y0 = fmaf(blo(p0), al, y0); y0 = fmaf(bhi(p0), ah, y0);
        y1 = fmaf(blo(p1), al, y1); y1 = fmaf(bhi(p1), ah, y1);
        y2 = fmaf(blo(p2), al, y2); y2 = fmaf(bhi(p2), ah, y2);
        y3 = fmaf(blo(p3), al, y3); y3 = fmaf(bhi(p3), ah, y3);
        if (NP > 1) {
          const float bl2 = Ws[4096 + k * 64 + lane];
          const float bh2 = Ws[4096 + (k + 1) * 64 + lane];
          z0 = fmaf(blo(p0), bl2, z0); z0 = fmaf(bhi(p0), bh2, z0);
          z1 = fmaf(blo(p1), bl2, z1); z1 = fmaf(bhi(p1), bh2, z1);
          z2 = fmaf(blo(p2), bl2, z2); z2 = fmaf(bhi(p2), bh2, z2);
          z3 = fmaf(blo(p3), bl2, z3); z3 = fmaf(bhi(p3), bh2, z3);
        }
      }
    }
    Y0[(size_t)ru * 64 + lane] = f2b(y0);
    if (NP > 1) Y1[(size_t)ru * 64 + lane] = f2b(z0);
    if (ru + 1 < N) {
      Y0[(size_t)(ru + 1) * 64 + lane] = f2b(y1);
      if (NP > 1) Y1[(size_t)(ru + 1) * 64 + lane] = f2b(z1);
    }
    if (ru + 2 < N) {
      Y0[(size_t)(ru + 2) * 64 + lane] = f2b(y2);
      if (NP > 1) Y1[(size_t)(ru + 2) * 64 + lane] = f2b(z2);
    }
    if (ru + 3 < N) {
      Y0[(size_t)(ru + 3) * 64 + lane] = f2b(y3);
      if (NP > 1) Y1[(size_t)(ru + 3) * 64 + lane] = f2b(z3);
    }
  }
}

// ---- dual128_k<SHARED>: Y0=[A0,C0]@W0+b0 ; Y1=[A1,C1]@W1+b1 (bf16 I/O) ----
template <bool SHARED>
__global__ void dual128_k(const u16* __restrict__ A0, const u16* __restrict__ C0,
                          const u16* __restrict__ A1, const u16* __restrict__ C1,
                          const float* __restrict__ W0, const float* __restrict__ W1,
                          const float* __restrict__ b0, const float* __restrict__ b1,
                          u16* __restrict__ Y0, u16* __restrict__ Y1, int N) {
  __shared__ float Ws[2 * 8192];
  for (int i = threadIdx.x; i < 8192; i += 256) Ws[i] = W0[i];
  for (int i = threadIdx.x; i < 8192; i += 256) Ws[8192 + i] = W1[i];
  __syncthreads();
  const int lane = threadIdx.x & 63;
  const int gw = (blockIdx.x * 256 + threadIdx.x) >> 6;
  const int nw = (gridDim.x * 256) >> 6;
  const float bj0 = b0[lane], bj1 = b1[lane];
  for (int r0 = gw * 4; r0 < N; r0 += nw * 4) {
    const int ru = __builtin_amdgcn_readfirstlane(r0);
    const int r1 = (ru + 1 < N) ? ru + 1 : ru;
    const int r2 = (ru + 2 < N) ? ru + 2 : ru;
    const int r3 = (ru + 3 < N) ? ru + 3 : ru;
    float ya0 = bj0, ya1 = bj0, ya2 = bj0, ya3 = bj0;
    float yb0 = bj1, yb1 = bj1, yb2 = bj1, yb3 = bj1;
    {
      const uint32* xr0 = (const uint32*)A0 + (size_t)ru * 32;
      const uint32* xr1 = (const uint32*)A0 + (size_t)r1 * 32;
      const uint32* xr2 = (const uint32*)A0 + (size_t)r2 * 32;
      const uint32* xr3 = (const uint32*)A0 + (size_t)r3 * 32;
#pragma unroll 1
      for (int kp = 0; kp < 32; kp += 8) {
#pragma unroll
        for (int j = 0; j < 8; ++j) {
          const uint32 p0 = xr0[kp + j], p1 = xr1[kp + j];
          const uint32 p2 = xr2[kp + j], p3 = xr3[kp + j];
          const int k = (kp + j) * 2;
          const float wl = Ws[k * 64 + lane], wh = Ws[(k + 1) * 64 + lane];
          ya0 = fmaf(blo(p0), wl, ya0); ya0 = fmaf(bhi(p0), wh, ya0);
          ya1 = fmaf(blo(p1), wl, ya1); ya1 = fmaf(bhi(p1), wh, ya1);
          ya2 = fmaf(blo(p2), wl, ya2); ya2 = fmaf(bhi(p2), wh, ya2);
          ya3 = fmaf(blo(p3), wl, ya3); ya3 = fmaf(bhi(p3), wh, ya3);
        }
      }
    }
    {
      const uint32* xr0 = (const uint32*)A1 + (size_t)ru * 32;
      const uint32* xr1 = (const uint32*)A1 + (size_t)r1 * 32;
      const uint32* xr2 = (const uint32*)A1 + (size_t)r2 * 32;
      const uint32* xr3 = (const uint32*)A1 + (size_t)r3 * 32;
#pragma unroll 1
      for (int kp = 0; kp < 32; kp += 8) {
#pragma unroll
        for (int j = 0; j < 8; ++j) {
          const uint32 p0 = xr0[kp + j], p1 = xr1[kp + j];
          const uint32 p2 = xr2[kp + j], p3 = xr3[kp + j];
          const int k = (kp + j) * 2;
          const float wl = Ws[8192 + k * 64 + lane], wh = Ws[8192 + (k + 1) * 64 + lane];
          yb0 = fmaf(blo(p0), wl, yb0); yb0 = fmaf(bhi(p0), wh, yb0);
          yb1 = fmaf(blo(p1), wl, yb1); yb1 = fmaf(bhi(p1), wh, yb1);
          yb2 = fmaf(blo(p2), wl, yb2); yb2 = fmaf(bhi(p2), wh, yb2);
          yb3 = fmaf(blo(p3), wl, yb3); yb3 = fmaf(bhi(p3), wh, yb3);
        }
      }
    }
    if (SHARED) {
      const uint32* xr0 = (const uint32*)C0 + (size_t)ru * 32;
      const uint32* xr1 = (const uint32*)C0 + (size_t)r1 * 32;
      const uint32* xr2 = (const uint32*)C0 + (size_t)r2 * 32;
      const uint32* xr3 = (const uint32*)C0 + (size_t)r3 * 32;
#pragma unroll 1
      for (int kp = 0; kp < 32; kp += 8) {
#pragma unroll
        for (int j = 0; j < 8; ++j) {
          const uint32 p0 = xr0[kp + j], p1 = xr1[kp + j];
          const uint32 p2 = xr2[kp + j], p3 = xr3[kp + j];
          const int k = 64 + (kp + j) * 2;
          const float al = Ws[k * 64 + lane], ah = Ws[(k + 1) * 64 + lane];
          const float bl2 = Ws[8192 + k * 64 + lane], bh2 = Ws[8192 + (k + 1) * 64 + lane];
          ya0 = fmaf(blo(p0), al, ya0); ya0 = fmaf(bhi(p0), ah, ya0);
          yb0 = fmaf(blo(p0), bl2, yb0); yb0 = fmaf(bhi(p0), bh2, yb0);
          ya1 = fmaf(blo(p1), al, ya1); ya1 = fmaf(bhi(p1), ah, ya1);
          yb1 = fmaf(blo(p1), bl2, yb1); yb1 = fmaf(bhi(p1), bh2, yb1);
          ya2 = fmaf(blo(p2), al, ya2); ya2 = fmaf(bhi(p2), ah, ya2);
          yb2 = fmaf(blo(p2), bl2, yb2); yb2 = fmaf(bhi(p2), bh2, yb2);
          ya3 = fmaf(blo(p3), al, ya3); ya3 = fmaf(bhi(p3), ah, ya3);
          yb3 = fmaf(blo(p3), bl2, yb3); yb3 = fmaf(bhi(p3), bh2, yb3);
        }
      }
    } else {
      {
        const uint32* xr0 = (const uint32*)C0 + (size_t)ru * 32;
        const uint32* xr1 = (const uint32*)C0 + (size_t)r1 * 32;
        const uint32* xr2 = (const uint32*)C0 + (size_t)r2 * 32;
        const uint32* xr3 = (const uint32*)C0 + (size_t)r3 * 32;
#pragma unroll 1
        for (int kp = 0; kp < 32; kp += 8) {
#pragma unroll
          for (int j = 0; j < 8; ++j) {
            const uint32 p0 = xr0[kp + j], p1 = xr1[kp + j];
            const uint32 p2 = xr2[kp + j], p3 = xr3[kp + j];
            const int k = 64 + (kp + j) * 2;
            const float wl = Ws[k * 64 + lane], wh = Ws[(k + 1) * 64 + lane];
            ya0 = fmaf(blo(p0), wl, ya0); ya0 = fmaf(bhi(p0), wh, ya0);
            ya1 = fmaf(blo(p1), wl, ya1); ya1 = fmaf(bhi(p1), wh, ya1);
            ya2 = fmaf(blo(p2), wl, ya2); ya2 = fmaf(bhi(p2), wh, ya2);
            ya3 = fmaf(blo(p3), wl, ya3); ya3 = fmaf(bhi(p3), wh, ya3);
          }
        }
      }
      {
        const uint32* xr0 = (const uint32*)C1 + (size_t)ru * 32;
        const uint32* xr1 = (const uint32*)C1 + (size_t)r1 * 32;
        const uint32* xr2 = (const uint32*)C1 + (size_t)r2 * 32;
        const uint32* xr3 = (const uint32*)C1 + (size_t)r3 * 32;
#pragma unroll 1
        for (int kp = 0; kp < 32; kp += 8) {
#pragma unroll
          for (int j = 0; j < 8; ++j) {
            const uint32 p0 = xr0[kp + j], p1 = xr1[kp + j];
            const uint32 p2 = xr2[kp + j], p3 = xr3[kp + j];
            const int k = 64 + (kp + j) * 2;
            const float wl = Ws[8192 + k * 64 + lane], wh = Ws[8192 + (k + 1) * 64 + lane];
            yb0 = fmaf(blo(p0), wl, yb0); yb0 = fmaf(bhi(p0), wh, yb0);
            yb1 = fmaf(blo(p1), wl, yb1); yb1 = fmaf(bhi(p1), wh, yb1);
            yb2 = fmaf(blo(p2), wl, yb2); yb2 = fmaf(bhi(p2), wh, yb2);
            yb3 = fmaf(blo(p3), wl, yb3); yb3 = fmaf(bhi(p3), wh, yb3);
          }
        }
      }
    }
    Y0[(size_t)ru * 64 + lane] = f2b(ya0);
    Y1[(size_t)ru * 64 + lane] = f2b(yb0);
    if (ru + 1 < N) { Y0[(size_t)(ru + 1) * 64 + lane] = f2b(ya1); Y1[(size_t)(ru + 1) * 64 + lane] = f2b(yb1); }
    if (ru + 2 < N) { Y0[(size_t)(ru + 2) * 64 + lane] = f2b(ya2); Y1[(size_t)(ru + 2) * 64 + lane] = f2b(yb2); }
    if (ru + 3 < N) { Y0[(size_t)(ru + 3) * 64 + lane] = f2b(ya3); Y1[(size_t)(ru + 3) * 64 + lane] = f2b(yb3); }
  }
}

// ========================= CSR build (counting sort) =======================
__global__ void hist_k(const int* __restrict__ key, int* __restrict__ cnt, int E) {
  const int e = blockIdx.x * blockDim.x + threadIdx.x;
  if (e < E) atomicAdd(cnt + key[e], 1);
}

__global__ void scan1_k(const int* __restrict__ in, int* __restrict__ out,
                        int* __restrict__ bsum, int n) {
  __shared__ int tmp[256];
  const int t = threadIdx.x;
  const int base = blockIdx.x * 1024 + t * 4;
  int v0 = (base + 0 < n) ? in[base + 0] : 0;
  int v1 = (base + 1 < n) ? in[base + 1] : 0;
  int v2 = (base + 2 < n) ? in[base + 2] : 0;
  int v3 = (base + 3 < n) ? in[base + 3] : 0;
  const int s = v0 + v1 + v2 + v3;
  tmp[t] = s;
  __syncthreads();
  for (int off = 1; off < 256; off <<= 1) {
    const int x = (t >= off) ? tmp[t - off] : 0;
    __syncthreads();
    tmp[t] += x;
    __syncthreads();
  }
  const int excl = tmp[t] - s;
  if (t == 255) bsum[blockIdx.x] = tmp[255];
  if (base + 0 < n) out[base + 0] = excl;
  if (base + 1 < n) out[base + 1] = excl + v0;
  if (base + 2 < n) out[base + 2] = excl + v0 + v1;
  if (base + 3 < n) out[base + 3] = excl + v0 + v1 + v2;
}
__global__ void scan2_k(int* __restrict__ bsum, int nb) {
  if (threadIdx.x == 0) {
    int acc = 0;
    for (int i = 0; i < nb; ++i) { const int v = bsum[i]; bsum[i] = acc; acc += v; }
  }
}
__global__ void scan3_k(int* __restrict__ out, const int* __restrict__ bsum, int n) {
  const int i = blockIdx.x * blockDim.x + threadIdx.x;
  if (i < n) out[i] += bsum[i >> 10];
}

__global__ void scatter_k(const int* __restrict__ key, const int* __restrict__ other,
                          int* __restrict__ cursor, int* __restrict__ srt, int E) {
  const int e = blockIdx.x * blockDim.x + threadIdx.x;
  if (e < E) {
    const int p = atomicAdd(cursor + key[e], 1);
    srt[p] = other[e];
  }
}

// =================== 32-lane-subwave edge kernels (bf16) ===================
// GATv2 aggregate+normalize; 2 dst nodes per wave (one per 32-lane half).
__global__ void gat32_k(const u16* __restrict__ fs, const u16* __restrict__ fd,
                        const float* __restrict__ attn,
                        const int* __restrict__ rowptr, const int* __restrict__ nbr,
                        u16* __restrict__ out, int N) {
  const int lane = threadIdx.x & 63;
  const int l = lane & 31, half = lane >> 5;
  const int wid = (blockIdx.x * blockDim.x + threadIdx.x) >> 6;
  const int nw = (gridDim.x * blockDim.x) >> 6;
  const float awlo = attn[2 * l], awhi = attn[2 * l + 1];
  const uint32* fs32 = (const uint32*)fs;
  const uint32* fd32 = (const uint32*)fd;
  uint32* out32 = (uint32*)out;
  for (int n0 = wid * 2; n0 < N; n0 += nw * 2) {
    const int n = n0 + half;
    const bool act = n < N;
    const int beg = act ? rowptr[n] : 0;
    const int end = act ? rowptr[n + 1] : 0;
    float fdlo = 0.0f, fdhi = 0.0f;
    if (act) {
      const uint32 fp = fd32[(size_t)n * 32 + l];
      fdlo = blo(fp); fdhi = bhi(fp);
    }
    float aclo = 0.0f, achi = 0.0f, den = 0.0f;
    int e = beg;
    for (; e + 1 < end; e += 2) {
      const int s0 = nbr[e], s1 = nbr[e + 1];
      const uint32 f0 = fs32[(size_t)s0 * 32 + l];
      const uint32 f1 = fs32[(size_t)s1 * 32 + l];
      const float f0l = blo(f0), f0h = bhi(f0);
      const float f1l = blo(f1), f1h = bhi(f1);
      float v0l = f0l + fdlo; v0l = v0l > 0.0f ? v0l : LRELU_SLOPE * v0l;
      float v0h = f0h + fdhi; v0h = v0h > 0.0f ? v0h : LRELU_SLOPE * v0h;
      float v1l = f1l + fdlo; v1l = v1l > 0.0f ? v1l : LRELU_SLOPE * v1l;
      float v1h = f1h + fdhi; v1h = v1h > 0.0f ? v1h : LRELU_SLOPE * v1h;
      float p0 = fmaf(v0l, awlo, v0h * awhi);
      float p1 = fmaf(v1l, awlo, v1h * awhi);
#pragma unroll
      for (int o = 16; o; o >>= 1) {
        p0 += __shfl_xor(p0, o, 64);
        p1 += __shfl_xor(p1, o, 64);
      }
      const float e0 = __expf(p0), e1 = __expf(p1);
      den += e0 + e1;
      aclo = fmaf(e0, f0l, aclo); achi = fmaf(e0, f0h, achi);
      aclo = fmaf(e1, f1l, aclo); achi = fmaf(e1, f1h, achi);
    }
    if (e < end) {
      const int s0 = nbr[e];
      const uint32 f0 = fs32[(size_t)s0 * 32 + l];
      const float f0l = blo(f0), f0h = bhi(f0);
      float v0l = f0l + fdlo; v0l = v0l > 0.0f ? v0l : LRELU_SLOPE * v0l;
      float v0h = f0h + fdhi; v0h = v0h > 0.0f ? v0h : LRELU_SLOPE * v0h;
      float p0 = fmaf(v0l, awlo, v0h * awhi);
#pragma unroll
      for (int o = 16; o; o >>= 1) p0 += __shfl_xor(p0, o, 64);
      const float e0 = __expf(p0);
      den += e0;
      aclo = fmaf(e0, f0l, aclo); achi = fmaf(e0, f0h, achi);
    }
    const float inv = den > 0.0f ? 1.0f / den : 0.0f;
    if (act) out32[(size_t)n * 32 + l] = packb(aclo * inv, achi * inv);
  }
}

// Fused Cheb step (MODE 1: T1; MODE 2: T2); 2 nodes per wave.
template <int MODE>
__global__ void cheb32_k(const u16* __restrict__ x, const u16* __restrict__ T0,
                         const u16* __restrict__ Tp, const float* __restrict__ dinv,
                         const float* __restrict__ lam,
                         const int* __restrict__ rowptr, const int* __restrict__ nbr,
                         u16* __restrict__ outT, int N) {
  const float re = 2.0f / lam[0];
  const int lane = threadIdx.x & 63;
  const int l = lane & 31, half = lane >> 5;
  const int wid = (blockIdx.x * blockDim.x + threadIdx.x) >> 6;
  const int nw = (gridDim.x * blockDim.x) >> 6;
  const uint32* x32 = (const uint32*)x;
  const uint32* T032 = (const uint32*)T0;
  const uint32* Tp32 = (const uint32*)Tp;
  uint32* o32 = (uint32*)outT;
  for (int n0 = wid * 2; n0 < N; n0 += nw * 2) {
    const int n = n0 + half;
    const bool act = n < N;
    const int beg = act ? rowptr[n] : 0;
    const int end = act ? rowptr[n + 1] : 0;
    float aclo = 0.0f, achi = 0.0f;
    int e = beg;
    for (; e + 1 < end; e += 2) {
      const int s0 = nbr[e], s1 = nbr[e + 1];
      const uint32 f0 = x32[(size_t)s0 * 32 + l];
      const uint32 f1 = x32[(size_t)s1 * 32 + l];
      const float d0 = dinv[s0], d1 = dinv[s1];
      aclo = fmaf(blo(f0), d0, aclo); achi = fmaf(bhi(f0), d0, achi);
      aclo = fmaf(blo(f1), d1, aclo); achi = fmaf(bhi(f1), d1, achi);
    }
    if (e < end) {
      const int s0 = nbr[e];
      const uint32 f0 = x32[(size_t)s0 * 32 + l];
      const float d0 = dinv[s0];
      aclo = fmaf(blo(f0), d0, aclo); achi = fmaf(bhi(f0), d0, achi);
    }
    if (!act) continue;
    const float dn = dinv[n];
    const float hl = aclo * dn, hh = achi * dn;
    float rl, rh;
    if (MODE == 1) {
      const uint32 t0 = T032[(size_t)n * 32 + l];
      rl = -re * hl + (re - 1.0f) * blo(t0);
      rh = -re * hh + (re - 1.0f) * bhi(t0);
    } else {
      const uint32 t0 = T032[(size_t)n * 32 + l];
      const uint32 tp = Tp32[(size_t)n * 32 + l];
      rl = -2.0f * re * hl + 2.0f * (re - 1.0f) * blo(tp) - blo(t0);
      rh = -2.0f * re * hh + 2.0f * (re - 1.0f) * bhi(tp) - bhi(t0);
    }
    o32[(size_t)n * 32 + l] = packb(rl, rh);
  }
}

__global__ void dinv_k(const int* __restrict__ rowptr, float* __restrict__ dinv, int N) {
  const int i = blockIdx.x * blockDim.x + threadIdx.x;
  if (i < N) {
    const float deg = (float)(rowptr[i + 1] - rowptr[i]);
    dinv[i] = rsqrtf(fmaxf(deg, 1.0f));
  }
}

// ---- mutualistic (bf16 I/O) ----
__global__ void mut_k(const u16* __restrict__ hP, const u16* __restrict__ hS,
                      u16* __restrict__ mP, u16* __restrict__ mS, int N) {
  const int lane = threadIdx.x & 63;
  const int u = (blockIdx.x * blockDim.x + threadIdx.x) >> 6;
  if (u >= N) return;
  const float p = b2f(hP[(size_t)u * 64 + lane]);
  const float s = b2f(hS[(size_t)u * 64 + lane]);
  const float m = p * s;
  float mxp = p, mxs = s;
#pragma unroll
  for (int o = 32; o; o >>= 1) {
    mxp = fmaxf(mxp, __shfl_xor(mxp, o, 64));
    mxs = fmaxf(mxs, __shfl_xor(mxs, o, 64));
  }
  const float ep = __expf(p - mxp);
  const float es = __expf(s - mxs);
  float sp = ep, ss = es;
#pragma unroll
  for (int o = 32; o; o >>= 1) {
    sp += __shfl_xor(sp, o, 64);
    ss += __shfl_xor(ss, o, 64);
  }
  mP[(size_t)u * 64 + lane] = f2b(m * (ep / sp));
  mS[(size_t)u * 64 + lane] = f2b(m * (es / ss));
}

// ---- edge dot: 4 edges/iter (2 halves x ILP-2), packed bf16 math ----
__global__ void dot32_k(const u16* __restrict__ A, const u16* __restrict__ Bm,
                        const int* __restrict__ src, const int* __restrict__ dst,
                        float* __restrict__ out, int E) {
  const int lane = threadIdx.x & 63;
  const int l = lane & 31, half = lane >> 5;
  const int wid = (blockIdx.x * blockDim.x + threadIdx.x) >> 6;
  const int nw = (gridDim.x * blockDim.x) >> 6;
  const uint32* A32 = (const uint32*)A;
  const uint32* B32 = (const uint32*)Bm;
  for (int e0 = wid * 4; e0 < E; e0 += nw * 4) {
    const int eA = e0 + half;
    const int eB = e0 + 2 + half;
    const int eAc = eA < E ? eA : E - 1;
    const int eBc = eB < E ? eB : E - 1;
    const int sA = src[eAc], dA = dst[eAc];
    const int sB = src[eBc], dB = dst[eBc];
    const uint32 a0 = A32[(size_t)sA * 32 + l];
    const uint32 b0 = B32[(size_t)dA * 32 + l];
    const uint32 a1 = A32[(size_t)sB * 32 + l];
    const uint32 b1 = B32[(size_t)dB * 32 + l];
    float p0 = fmaf(blo(a0), blo(b0), bhi(a0) * bhi(b0));
    float p1 = fmaf(blo(a1), blo(b1), bhi(a1) * bhi(b1));
#pragma unroll
    for (int o = 16; o; o >>= 1) {
      p0 += __shfl_xor(p0, o, 64);
      p1 += __shfl_xor(p1, o, 64);
    }
    if (l == 0) {
      if (eA < E) out[eA] = p0;
      if (eB < E) out[eB] = p1;
    }
  }
}

// ---------------------------------------------------------------------------

static void build_csr(const int* key, const int* other, int E, int N,
                      int* rowptr, int* srt, int* cursor, int* bsum,
                      hipStream_t stream) {
  const int n1 = N + 1;
  hipMemsetAsync(cursor, 0, (size_t)n1 * 4, stream);
  hist_k<<<(E + 255) / 256, 256, 0, stream>>>(key, cursor, E);
  const int nb = (n1 + 1023) / 1024;
  scan1_k<<<nb, 256, 0, stream>>>(cursor, rowptr, bsum, n1);
  scan2_k<<<1, 64, 0, stream>>>(bsum, nb);
  scan3_k<<<(n1 + 255) / 256, 256, 0, stream>>>(rowptr, bsum, n1);
  hipMemcpyAsync(cursor, rowptr, (size_t)N * 4, hipMemcpyDeviceToDevice, stream);
  scatter_k<<<(E + 255) / 256, 256, 0, stream>>>(key, other, cursor, srt, E);
}

extern "C" void kernel_launch(void* const* d_in, const int* in_sizes, int n_in,
                              void* d_out, int out_size, void* d_ws, size_t ws_size,
                              hipStream_t stream) {
  const float* user_emb = (const float*)d_in[0];
  const float* item_emb = (const float*)d_in[1];
  const int* rate_src = (const int*)d_in[2];
  const int* rate_dst = (const int*)d_in[3];
  const int* link_src = (const int*)d_in[4];
  const int* link_dst = (const int*)d_in[5];
  const int* neg_rate_src = (const int*)d_in[6];
  const int* neg_rate_dst = (const int*)d_in[7];
  const int* neg_link_src = (const int*)d_in[8];
  const int* neg_link_dst = (const int*)d_in[9];
  const float* lam = (const float*)d_in[10];
  const float* gat_Wsrc = (const float*)d_in[11];
  const float* gat_bsrc = (const float*)d_in[12];
  const float* gat_Wdst = (const float*)d_in[13];
  const float* gat_bdst = (const float*)d_in[14];
  const float* gat_attn = (const float*)d_in[15];
  const float* W_out = (const float*)d_in[16];
  const float* b_out = (const float*)d_in[17];
  const float* cheb_W = (const float*)d_in[18];
  const float* cheb_b = (const float*)d_in[19];
  const float* Wc = (const float*)d_in[20];
  const float* bc = (const float*)d_in[21];
  const float* Wsm = (const float*)d_in[22];
  const float* bs = (const float*)d_in[23];
  const float* WpP = (const float*)d_in[24];
  const float* bpP = (const float*)d_in[25];
  const float* WpS = (const float*)d_in[26];
  const float* bpS = (const float*)d_in[27];

  const int NU = in_sizes[0] / 64;
  const int NI = in_sizes[1] / 64;
  const int NR = in_sizes[2];
  const int NL = in_sizes[4];
  const int NMAX = NU > NI ? NU : NI;
  const size_t MAT = (size_t)NMAX * 64;

  u16* ub = (u16*)d_ws;                       // user_emb bf16 copy
  u16* ib = ub + (size_t)NU * 64;             // item_emb bf16 copy
  u16* B0 = ib + (size_t)NI * 64;
  u16* B1 = B0 + MAT;
  u16* B2 = B1 + MAT;
  u16* B3 = B2 + MAT;
  u16* B4 = B3 + MAT;
  u16* B5 = B4 + MAT;
  u16* B6 = B5 + MAT;
  u16* B7 = B6 + MAT;
  int* ip = (int*)(B7 + MAT);
  int* rp_rd = ip;                   // NI+1
  int* rp_rs = rp_rd + (NI + 1);     // NU+1
  int* rp_ld = rp_rs + (NU + 1);     // NU+1
  int* srt_rd = rp_ld + (NU + 1);    // NR
  int* srt_rs = srt_rd + NR;         // NR
  int* srt_ld = srt_rs + NR;         // NL
  int* cursor = srt_ld + NL;         // NMAX+1
  int* bsum = cursor + (NMAX + 1);   // 256
  float* dinv = (float*)(bsum + 256);  // NU

  const int W64 = 64 * 64, B64 = 64;

  // ---- bf16 copies of embeddings ----
  cvt_k<<<1024, 256, 0, stream>>>((const float4*)user_emb, (ushort4*)ub, NU * 16);
  cvt_k<<<1024, 256, 0, stream>>>((const float4*)item_emb, (ushort4*)ib, NI * 16);

  // ---- 3 CSR groupings ----
  build_csr(rate_dst, rate_src, NR, NI, rp_rd, srt_rd, cursor, bsum, stream);
  build_csr(rate_src, rate_dst, NR, NU, rp_rs, srt_rs, cursor, bsum, stream);
  build_csr(link_dst, link_src, NL, NU, rp_ld, srt_ld, cursor, bsum, stream);

  // ---- user projections: fs0->B0, fd1->B1 ; fd2->B2, fd3->B3 ----
  proj_k<2><<<GEMM_BLOCKS, 256, 0, stream>>>(
      ub, gat_Wsrc + 0 * W64, gat_Wdst + 1 * W64,
      gat_bsrc + 0 * B64, gat_bdst + 1 * B64, B0, B1, NU);
  proj_k<2><<<GEMM_BLOCKS, 256, 0, stream>>>(
      ub, gat_Wdst + 2 * W64, gat_Wdst + 3 * W64,
      gat_bdst + 2 * B64, gat_bdst + 3 * B64, B2, B3, NU);
  // ---- item projections: fd0->B4, fs1->B5 ----
  proj_k<2><<<GEMM_BLOCKS, 256, 0, stream>>>(
      ib, gat_Wdst + 0 * W64, gat_Wsrc + 1 * W64,
      gat_bdst + 0 * B64, gat_bsrc + 1 * B64, B4, B5, NI);

  // ---- gat0: (fs=B0, fd=B4) over rate-by-item -> B6 (h1_item) ----
  gat32_k<<<EDGE_BLOCKS, 256, 0, stream>>>(B0, B4, gat_attn + 0 * B64, rp_rd, srt_rd, B6, NI);
  // ---- gat1: (fs=B5, fd=B1) over rate-by-user -> B7 (h2_user) ----
  gat32_k<<<EDGE_BLOCKS, 256, 0, stream>>>(B5, B1, gat_attn + 1 * B64, rp_rs, srt_rs, B7, NU);

  // ---- fs2 = h1_item @ Ws2 -> B0 ; gat2 (fs=B0, fd=B2) -> B4 (item_infl) ----
  proj_k<1><<<GEMM_BLOCKS, 256, 0, stream>>>(
      B6, gat_Wsrc + 2 * W64, nullptr, gat_bsrc + 2 * B64, nullptr, B0, nullptr, NI);
  gat32_k<<<EDGE_BLOCKS, 256, 0, stream>>>(B0, B2, gat_attn + 2 * B64, rp_rs, srt_rs, B4, NU);

  // ---- fs3 = h2_user @ Ws3 -> B5 ; gat3 (fs=B5, fd=B3) -> B2 (social_item) ----
  proj_k<1><<<GEMM_BLOCKS, 256, 0, stream>>>(
      B7, gat_Wsrc + 3 * W64, nullptr, gat_bsrc + 3 * B64, nullptr, B5, nullptr, NU);
  gat32_k<<<EDGE_BLOCKS, 256, 0, stream>>>(B5, B3, gat_attn + 3 * B64, rp_ld, srt_ld, B2, NU);

  // ---- user_pref = [item_infl(B4), social_item(B2)] @ W_out + b_out -> B0 ----
  gemm_multi_k<2><<<GEMM_BLOCKS, 256, 0, stream>>>(B4, B2, nullptr, W_out, b_out, B0, NU);

  // ---- ChebConv(k=3): T1->B5, T2->B3, rst->B6 ----
  dinv_k<<<(NU + 255) / 256, 256, 0, stream>>>(rp_ld, dinv, NU);
  cheb32_k<1><<<EDGE_BLOCKS, 256, 0, stream>>>(ub, ub, nullptr, dinv, lam,
                                               rp_ld, srt_ld, B5, NU);
  cheb32_k<2><<<EDGE_BLOCKS, 256, 0, stream>>>(B5, ub, B5, dinv, lam,
                                               rp_ld, srt_ld, B3, NU);
  gemm_multi_k<3><<<GEMM_BLOCKS, 256, 0, stream>>>(ub, B5, B3, cheb_W, cheb_b, B6, NU);

  // ---- rst projections: fs4->B4, fd4->B2 ; gat4 -> B5 (user_social) ----
  proj_k<2><<<GEMM_BLOCKS, 256, 0, stream>>>(
      B6, gat_Wsrc + 4 * W64, gat_Wdst + 4 * W64,
      gat_bsrc + 4 * B64, gat_bdst + 4 * B64, B4, B2, NU);
  gat32_k<<<EDGE_BLOCKS, 256, 0, stream>>>(B4, B2, gat_attn + 4 * B64, rp_ld, srt_ld, B5, NU);

  // ---- mutualistic: h_uP->B4, h_uS->B2 (shared ub read) ----
  dual128_k<true><<<DUAL_BLOCKS, 256, 0, stream>>>(
      B0, ub, B5, nullptr, Wc, Wsm, bc, bs, B4, B2, NU);
  mut_k<<<(NU + 3) / 4, 256, 0, stream>>>(B4, B2, B3, B7, NU);  // mP->B3, mS->B7
  // h_new_P->B0, h_new_S->B5
  dual128_k<false><<<DUAL_BLOCKS, 256, 0, stream>>>(
      B3, B4, B7, B2, WpP, WpS, bpP, bpS, B0, B5, NU);

  // ---- predictors ----
  float* out = (float*)d_out;
  dot32_k<<<EDGE_BLOCKS, 256, 0, stream>>>(B0, ib, rate_src, rate_dst, out, NR);
  dot32_k<<<EDGE_BLOCKS, 256, 0, stream>>>(B0, ib, neg_rate_src, neg_rate_dst, out + NR, NR);
  dot32_k<<<EDGE_BLOCKS, 256, 0, stream>>>(B5, ub, link_src, link_dst, out + 2 * (size_t)NR, NL);
  dot32_k<<<EDGE_BLOCKS, 256, 0, stream>>>(B5, ub, neg_link_src, neg_link_dst, out + 2 * (size_t)NR + NL, NL);
}

// Round 15
// 988.330 us; speedup vs baseline: 2.5879x; 1.3055x over previous
//
#include <hip/hip_runtime.h>

// ---------------------------------------------------------------------------
// MutualRec forward: 5x GATv2 + ChebConv(k=3) + mutualistic MLP + edge dots
// R15: GEMM family -> MFMA (v_mfma_f32_16x16x32_bf16). One wave = 16x64
//   output tile, 8 mfma. W pre-shuffled into lane-ordered bf16 frag buffers
//   (prep kernel); B-frags live in VGPRs across tiles. No LDS, no barriers.
//   Edge kernels (32-lane subwave bf16) and CSR build unchanged from R14.
// ---------------------------------------------------------------------------

#define LRELU_SLOPE 0.2f
#define MFMA_BLOCKS 1024
#define EDGE_BLOCKS 2048

typedef unsigned short u16;
typedef unsigned int uint32;
typedef __attribute__((ext_vector_type(8))) short short8;
typedef __attribute__((ext_vector_type(4))) float f32x4;

__device__ __forceinline__ float b2f(u16 u) {
  return __uint_as_float(((uint32)u) << 16);
}
__device__ __forceinline__ u16 f2b(float f) {
  uint32 u = __float_as_uint(f);
  uint32 r = (u + 0x7fffu + ((u >> 16) & 1u)) >> 16;
  return (u16)r;
}
__device__ __forceinline__ float blo(uint32 p) { return __uint_as_float(p << 16); }
__device__ __forceinline__ float bhi(uint32 p) { return __uint_as_float(p & 0xffff0000u); }
__device__ __forceinline__ uint32 packb(float lo, float hi) {
  return (uint32)f2b(lo) | ((uint32)f2b(hi) << 16);
}

// ---- f32 -> bf16 table conversion (vectorized) ----
__global__ void cvt_k(const float4* __restrict__ X, ushort4* __restrict__ Y, int n4) {
  const int stride = gridDim.x * blockDim.x;
  for (int i = blockIdx.x * blockDim.x + threadIdx.x; i < n4; i += stride) {
    const float4 v = X[i];
    ushort4 o;
    o.x = f2b(v.x); o.y = f2b(v.y); o.z = f2b(v.z); o.w = f2b(v.w);
    Y[i] = o;
  }
}

// ---- W[nmat][64][64] f32 -> lane-ordered bf16 B-fragments ----
// fb[mat*4096 + l*64 + kc*32 + cb*8 + j] = bf16( W[mat][kc*32+(l>>4)*8+j][cb*16+(l&15)] )
__global__ void wfrag_k(const float* __restrict__ W, u16* __restrict__ fb, int nmat) {
  const int total = nmat * 4096;
  const int stride = gridDim.x * blockDim.x;
  for (int i = blockIdx.x * blockDim.x + threadIdx.x; i < total; i += stride) {
    const int mat = i >> 12, rem = i & 4095;
    const int l = rem >> 6, r = rem & 63;
    const int kc = r >> 5, cb = (r >> 3) & 3, j = r & 7;
    const int k = kc * 32 + ((l >> 4) & 3) * 8 + j;
    const int col = cb * 16 + (l & 15);
    fb[i] = f2b(W[(size_t)mat * 4096 + k * 64 + col]);
  }
}

// ---- MFMA GEMM: Y[N,64] = sum_i X_i[N,64] @ W_i + b  (bf16 I/O, f32 acc) ----
template <int NIN>
__global__ void mfma_g_k(const u16* __restrict__ X0, const u16* __restrict__ X1,
                         const u16* __restrict__ X2,
                         const u16* __restrict__ F0, const u16* __restrict__ F1,
                         const u16* __restrict__ F2,
                         const float* __restrict__ b, u16* __restrict__ Y, int N) {
  const int lane = threadIdx.x & 63;
  const int gw = (blockIdx.x * blockDim.x + threadIdx.x) >> 6;
  const int nw = (gridDim.x * blockDim.x) >> 6;
  const int lo = lane & 15, hi = lane >> 4;
  // B fragments: NIN x 2 kchunks x 4 colblocks, 8 bf16 each (VGPR-resident)
  short8 bf[NIN][2][4];
#pragma unroll
  for (int i = 0; i < NIN; ++i) {
    const u16* Fi = (i == 0) ? F0 : ((i == 1) ? F1 : F2);
#pragma unroll
    for (int kc = 0; kc < 2; ++kc)
#pragma unroll
      for (int cb = 0; cb < 4; ++cb)
        bf[i][kc][cb] = *(const short8*)(Fi + (size_t)lane * 64 + kc * 32 + cb * 8);
  }
  float bcol[4];
#pragma unroll
  for (int cb = 0; cb < 4; ++cb) bcol[cb] = b[cb * 16 + lo];
  const int ntile = (N + 15) >> 4;
  for (int t = gw; t < ntile; t += nw) {
    int arow = t * 16 + lo;
    if (arow >= N) arow = N - 1;
    f32x4 acc[4];
#pragma unroll
    for (int cb = 0; cb < 4; ++cb) {
      acc[cb][0] = bcol[cb]; acc[cb][1] = bcol[cb];
      acc[cb][2] = bcol[cb]; acc[cb][3] = bcol[cb];
    }
#pragma unroll
    for (int i = 0; i < NIN; ++i) {
      const u16* Xi = (i == 0) ? X0 : ((i == 1) ? X1 : X2);
      const short8 a0 = *(const short8*)(Xi + (size_t)arow * 64 + hi * 8);
      const short8 a1 = *(const short8*)(Xi + (size_t)arow * 64 + 32 + hi * 8);
#pragma unroll
      for (int cb = 0; cb < 4; ++cb)
        acc[cb] = __builtin_amdgcn_mfma_f32_16x16x32_bf16(a0, bf[i][0][cb], acc[cb], 0, 0, 0);
#pragma unroll
      for (int cb = 0; cb < 4; ++cb)
        acc[cb] = __builtin_amdgcn_mfma_f32_16x16x32_bf16(a1, bf[i][1][cb], acc[cb], 0, 0, 0);
    }
#pragma unroll
    for (int cb = 0; cb < 4; ++cb) {
#pragma unroll
      for (int j = 0; j < 4; ++j) {
        const int row = t * 16 + hi * 4 + j;
        if (row < N) Y[(size_t)row * 64 + cb * 16 + lo] = f2b(acc[cb][j]);
      }
    }
  }
}

// ========================= CSR build (counting sort) =======================
__global__ void hist_k(const int* __restrict__ key, int* __restrict__ cnt, int E) {
  const int e = blockIdx.x * blockDim.x + threadIdx.x;
  if (e < E) atomicAdd(cnt + key[e], 1);
}

__global__ void scan1_k(const int* __restrict__ in, int* __restrict__ out,
                        int* __restrict__ bsum, int n) {
  __shared__ int tmp[256];
  const int t = threadIdx.x;
  const int base = blockIdx.x * 1024 + t * 4;
  int v0 = (base + 0 < n) ? in[base + 0] : 0;
  int v1 = (base + 1 < n) ? in[base + 1] : 0;
  int v2 = (base + 2 < n) ? in[base + 2] : 0;
  int v3 = (base + 3 < n) ? in[base + 3] : 0;
  const int s = v0 + v1 + v2 + v3;
  tmp[t] = s;
  __syncthreads();
  for (int off = 1; off < 256; off <<= 1) {
    const int x = (t >= off) ? tmp[t - off] : 0;
    __syncthreads();
    tmp[t] += x;
    __syncthreads();
  }
  const int excl = tmp[t] - s;
  if (t == 255) bsum[blockIdx.x] = tmp[255];
  if (base + 0 < n) out[base + 0] = excl;
  if (base + 1 < n) out[base + 1] = excl + v0;
  if (base + 2 < n) out[base + 2] = excl + v0 + v1;
  if (base + 3 < n) out[base + 3] = excl + v0 + v1 + v2;
}
__global__ void scan2_k(int* __restrict__ bsum, int nb) {
  if (threadIdx.x == 0) {
    int acc = 0;
    for (int i = 0; i < nb; ++i) { const int v = bsum[i]; bsum[i] = acc; acc += v; }
  }
}
__global__ void scan3_k(int* __restrict__ out, const int* __restrict__ bsum, int n) {
  const int i = blockIdx.x * blockDim.x + threadIdx.x;
  if (i < n) out[i] += bsum[i >> 10];
}

__global__ void scatter_k(const int* __restrict__ key, const int* __restrict__ other,
                          int* __restrict__ cursor, int* __restrict__ srt, int E) {
  const int e = blockIdx.x * blockDim.x + threadIdx.x;
  if (e < E) {
    const int p = atomicAdd(cursor + key[e], 1);
    srt[p] = other[e];
  }
}

// =================== 32-lane-subwave edge kernels (bf16) ===================
__global__ void gat32_k(const u16* __restrict__ fs, const u16* __restrict__ fd,
                        const float* __restrict__ attn,
                        const int* __restrict__ rowptr, const int* __restrict__ nbr,
                        u16* __restrict__ out, int N) {
  const int lane = threadIdx.x & 63;
  const int l = lane & 31, half = lane >> 5;
  const int wid = (blockIdx.x * blockDim.x + threadIdx.x) >> 6;
  const int nw = (gridDim.x * blockDim.x) >> 6;
  const float awlo = attn[2 * l], awhi = attn[2 * l + 1];
  const uint32* fs32 = (const uint32*)fs;
  const uint32* fd32 = (const uint32*)fd;
  uint32* out32 = (uint32*)out;
  for (int n0 = wid * 2; n0 < N; n0 += nw * 2) {
    const int n = n0 + half;
    const bool act = n < N;
    const int beg = act ? rowptr[n] : 0;
    const int end = act ? rowptr[n + 1] : 0;
    float fdlo = 0.0f, fdhi = 0.0f;
    if (act) {
      const uint32 fp = fd32[(size_t)n * 32 + l];
      fdlo = blo(fp); fdhi = bhi(fp);
    }
    float aclo = 0.0f, achi = 0.0f, den = 0.0f;
    int e = beg;
    for (; e + 1 < end; e += 2) {
      const int s0 = nbr[e], s1 = nbr[e + 1];
      const uint32 f0 = fs32[(size_t)s0 * 32 + l];
      const uint32 f1 = fs32[(size_t)s1 * 32 + l];
      const float f0l = blo(f0), f0h = bhi(f0);
      const float f1l = blo(f1), f1h = bhi(f1);
      float v0l = f0l + fdlo; v0l = v0l > 0.0f ? v0l : LRELU_SLOPE * v0l;
      float v0h = f0h + fdhi; v0h = v0h > 0.0f ? v0h : LRELU_SLOPE * v0h;
      float v1l = f1l + fdlo; v1l = v1l > 0.0f ? v1l : LRELU_SLOPE * v1l;
      float v1h = f1h + fdhi; v1h = v1h > 0.0f ? v1h : LRELU_SLOPE * v1h;
      float p0 = fmaf(v0l, awlo, v0h * awhi);
      float p1 = fmaf(v1l, awlo, v1h * awhi);
#pragma unroll
      for (int o = 16; o; o >>= 1) {
        p0 += __shfl_xor(p0, o, 64);
        p1 += __shfl_xor(p1, o, 64);
      }
      const float e0 = __expf(p0), e1 = __expf(p1);
      den += e0 + e1;
      aclo = fmaf(e0, f0l, aclo); achi = fmaf(e0, f0h, achi);
      aclo = fmaf(e1, f1l, aclo); achi = fmaf(e1, f1h, achi);
    }
    if (e < end) {
      const int s0 = nbr[e];
      const uint32 f0 = fs32[(size_t)s0 * 32 + l];
      const float f0l = blo(f0), f0h = bhi(f0);
      float v0l = f0l + fdlo; v0l = v0l > 0.0f ? v0l : LRELU_SLOPE * v0l;
      float v0h = f0h + fdhi; v0h = v0h > 0.0f ? v0h : LRELU_SLOPE * v0h;
      float p0 = fmaf(v0l, awlo, v0h * awhi);
#pragma unroll
      for (int o = 16; o; o >>= 1) p0 += __shfl_xor(p0, o, 64);
      const float e0 = __expf(p0);
      den += e0;
      aclo = fmaf(e0, f0l, aclo); achi = fmaf(e0, f0h, achi);
    }
    const float inv = den > 0.0f ? 1.0f / den : 0.0f;
    if (act) out32[(size_t)n * 32 + l] = packb(aclo * inv, achi * inv);
  }
}

template <int MODE>
__global__ void cheb32_k(const u16* __restrict__ x, const u16* __restrict__ T0,
                         const u16* __restrict__ Tp, const float* __restrict__ dinv,
                         const float* __restrict__ lam,
                         const int* __restrict__ rowptr, const int* __restrict__ nbr,
                         u16* __restrict__ outT, int N) {
  const float re = 2.0f / lam[0];
  const int lane = threadIdx.x & 63;
  const int l = lane & 31, half = lane >> 5;
  const int wid = (blockIdx.x * blockDim.x + threadIdx.x) >> 6;
  const int nw = (gridDim.x * blockDim.x) >> 6;
  const uint32* x32 = (const uint32*)x;
  const uint32* T032 = (const uint32*)T0;
  const uint32* Tp32 = (const uint32*)Tp;
  uint32* o32 = (uint32*)outT;
  for (int n0 = wid * 2; n0 < N; n0 += nw * 2) {
    const int n = n0 + half;
    const bool act = n < N;
    const int beg = act ? rowptr[n] : 0;
    const int end = act ? rowptr[n + 1] : 0;
    float aclo = 0.0f, achi = 0.0f;
    int e = beg;
    for (; e + 1 < end; e += 2) {
      const int s0 = nbr[e], s1 = nbr[e + 1];
      const uint32 f0 = x32[(size_t)s0 * 32 + l];
      const uint32 f1 = x32[(size_t)s1 * 32 + l];
      const float d0 = dinv[s0], d1 = dinv[s1];
      aclo = fmaf(blo(f0), d0, aclo); achi = fmaf(bhi(f0), d0, achi);
      aclo = fmaf(blo(f1), d1, aclo); achi = fmaf(bhi(f1), d1, achi);
    }
    if (e < end) {
      const int s0 = nbr[e];
      const uint32 f0 = x32[(size_t)s0 * 32 + l];
      const float d0 = dinv[s0];
      aclo = fmaf(blo(f0), d0, aclo); achi = fmaf(bhi(f0), d0, achi);
    }
    if (!act) continue;
    const float dn = dinv[n];
    const float hl = aclo * dn, hh = achi * dn;
    float rl, rh;
    if (MODE == 1) {
      const uint32 t0 = T032[(size_t)n * 32 + l];
      rl = -re * hl + (re - 1.0f) * blo(t0);
      rh = -re * hh + (re - 1.0f) * bhi(t0);
    } else {
      const uint32 t0 = T032[(size_t)n * 32 + l];
      const uint32 tp = Tp32[(size_t)n * 32 + l];
      rl = -2.0f * re * hl + 2.0f * (re - 1.0f) * blo(tp) - blo(t0);
      rh = -2.0f * re * hh + 2.0f * (re - 1.0f) * bhi(tp) - bhi(t0);
    }
    o32[(size_t)n * 32 + l] = packb(rl, rh);
  }
}

__global__ void dinv_k(const int* __restrict__ rowptr, float* __restrict__ dinv, int N) {
  const int i = blockIdx.x * blockDim.x + threadIdx.x;
  if (i < N) {
    const float deg = (float)(rowptr[i + 1] - rowptr[i]);
    dinv[i] = rsqrtf(fmaxf(deg, 1.0f));
  }
}

// ---- mutualistic (bf16 I/O) ----
__global__ void mut_k(const u16* __restrict__ hP, const u16* __restrict__ hS,
                      u16* __restrict__ mP, u16* __restrict__ mS, int N) {
  const int lane = threadIdx.x & 63;
  const int u = (blockIdx.x * blockDim.x + threadIdx.x) >> 6;
  if (u >= N) return;
  const float p = b2f(hP[(size_t)u * 64 + lane]);
  const float s = b2f(hS[(size_t)u * 64 + lane]);
  const float m = p * s;
  float mxp = p, mxs = s;
#pragma unroll
  for (int o = 32; o; o >>= 1) {
    mxp = fmaxf(mxp, __shfl_xor(mxp, o, 64));
    mxs = fmaxf(mxs, __shfl_xor(mxs, o, 64));
  }
  const float ep = __expf(p - mxp);
  const float es = __expf(s - mxs);
  float sp = ep, ss = es;
#pragma unroll
  for (int o = 32; o; o >>= 1) {
    sp += __shfl_xor(sp, o, 64);
    ss += __shfl_xor(ss, o, 64);
  }
  mP[(size_t)u * 64 + lane] = f2b(m * (ep / sp));
  mS[(size_t)u * 64 + lane] = f2b(m * (es / ss));
}

// ---- edge dot: 4 edges/iter (2 halves x ILP-2), packed bf16 math ----
__global__ void dot32_k(const u16* __restrict__ A, const u16* __restrict__ Bm,
                        const int* __restrict__ src, const int* __restrict__ dst,
                        float* __restrict__ out, int E) {
  const int lane = threadIdx.x & 63;
  const int l = lane & 31, half = lane >> 5;
  const int wid = (blockIdx.x * blockDim.x + threadIdx.x) >> 6;
  const int nw = (gridDim.x * blockDim.x) >> 6;
  const uint32* A32 = (const uint32*)A;
  const uint32* B32 = (const uint32*)Bm;
  for (int e0 = wid * 4; e0 < E; e0 += nw * 4) {
    const int eA = e0 + half;
    const int eB = e0 + 2 + half;
    const int eAc = eA < E ? eA : E - 1;
    const int eBc = eB < E ? eB : E - 1;
    const int sA = src[eAc], dA = dst[eAc];
    const int sB = src[eBc], dB = dst[eBc];
    const uint32 a0 = A32[(size_t)sA * 32 + l];
    const uint32 b0 = B32[(size_t)dA * 32 + l];
    const uint32 a1 = A32[(size_t)sB * 32 + l];
    const uint32 b1 = B32[(size_t)dB * 32 + l];
    float p0 = fmaf(blo(a0), blo(b0), bhi(a0) * bhi(b0));
    float p1 = fmaf(blo(a1), blo(b1), bhi(a1) * bhi(b1));
#pragma unroll
    for (int o = 16; o; o >>= 1) {
      p0 += __shfl_xor(p0, o, 64);
      p1 += __shfl_xor(p1, o, 64);
    }
    if (l == 0) {
      if (eA < E) out[eA] = p0;
      if (eB < E) out[eB] = p1;
    }
  }
}

// ---------------------------------------------------------------------------

static void build_csr(const int* key, const int* other, int E, int N,
                      int* rowptr, int* srt, int* cursor, int* bsum,
                      hipStream_t stream) {
  const int n1 = N + 1;
  hipMemsetAsync(cursor, 0, (size_t)n1 * 4, stream);
  hist_k<<<(E + 255) / 256, 256, 0, stream>>>(key, cursor, E);
  const int nb = (n1 + 1023) / 1024;
  scan1_k<<<nb, 256, 0, stream>>>(cursor, rowptr, bsum, n1);
  scan2_k<<<1, 64, 0, stream>>>(bsum, nb);
  scan3_k<<<(n1 + 255) / 256, 256, 0, stream>>>(rowptr, bsum, n1);
  hipMemcpyAsync(cursor, rowptr, (size_t)N * 4, hipMemcpyDeviceToDevice, stream);
  scatter_k<<<(E + 255) / 256, 256, 0, stream>>>(key, other, cursor, srt, E);
}

extern "C" void kernel_launch(void* const* d_in, const int* in_sizes, int n_in,
                              void* d_out, int out_size, void* d_ws, size_t ws_size,
                              hipStream_t stream) {
  const float* user_emb = (const float*)d_in[0];
  const float* item_emb = (const float*)d_in[1];
  const int* rate_src = (const int*)d_in[2];
  const int* rate_dst = (const int*)d_in[3];
  const int* link_src = (const int*)d_in[4];
  const int* link_dst = (const int*)d_in[5];
  const int* neg_rate_src = (const int*)d_in[6];
  const int* neg_rate_dst = (const int*)d_in[7];
  const int* neg_link_src = (const int*)d_in[8];
  const int* neg_link_dst = (const int*)d_in[9];
  const float* lam = (const float*)d_in[10];
  const float* gat_Wsrc = (const float*)d_in[11];
  const float* gat_bsrc = (const float*)d_in[12];
  const float* gat_Wdst = (const float*)d_in[13];
  const float* gat_bdst = (const float*)d_in[14];
  const float* gat_attn = (const float*)d_in[15];
  const float* W_out = (const float*)d_in[16];
  const float* b_out = (const float*)d_in[17];
  const float* cheb_W = (const float*)d_in[18];
  const float* cheb_b = (const float*)d_in[19];
  const float* Wc = (const float*)d_in[20];
  const float* bc = (const float*)d_in[21];
  const float* Wsm = (const float*)d_in[22];
  const float* bs = (const float*)d_in[23];
  const float* WpP = (const float*)d_in[24];
  const float* bpP = (const float*)d_in[25];
  const float* WpS = (const float*)d_in[26];
  const float* bpS = (const float*)d_in[27];

  const int NU = in_sizes[0] / 64;
  const int NI = in_sizes[1] / 64;
  const int NR = in_sizes[2];
  const int NL = in_sizes[4];
  const int NMAX = NU > NI ? NU : NI;
  const size_t MAT = (size_t)NMAX * 64;
  const int FR = 4096;  // u16 per frag mat

  u16* ub = (u16*)d_ws;
  u16* ib = ub + (size_t)NU * 64;
  u16* B0 = ib + (size_t)NI * 64;
  u16* B1 = B0 + MAT;
  u16* B2 = B1 + MAT;
  u16* B3 = B2 + MAT;
  u16* B4 = B3 + MAT;
  u16* B5 = B4 + MAT;
  u16* B6 = B5 + MAT;
  u16* B7 = B6 + MAT;
  u16* fb = B7 + MAT;               // 23 * 4096 u16 frag buffers
  u16* fbWsrc = fb;                 // 5
  u16* fbWdst = fb + 5 * FR;        // 5
  u16* fbWout = fb + 10 * FR;       // 2
  u16* fbCheb = fb + 12 * FR;       // 3
  u16* fbWc = fb + 15 * FR;         // 2
  u16* fbWsm = fb + 17 * FR;        // 2
  u16* fbWpP = fb + 19 * FR;        // 2
  u16* fbWpS = fb + 21 * FR;        // 2
  int* ip = (int*)(fb + 23 * FR);
  int* rp_rd = ip;
  int* rp_rs = rp_rd + (NI + 1);
  int* rp_ld = rp_rs + (NU + 1);
  int* srt_rd = rp_ld + (NU + 1);
  int* srt_rs = srt_rd + NR;
  int* srt_ld = srt_rs + NR;
  int* cursor = srt_ld + NL;
  int* bsum = cursor + (NMAX + 1);
  float* dinv = (float*)(bsum + 256);

  const int B64 = 64;

  // ---- bf16 copies + W fragment prep ----
  cvt_k<<<1024, 256, 0, stream>>>((const float4*)user_emb, (ushort4*)ub, NU * 16);
  cvt_k<<<1024, 256, 0, stream>>>((const float4*)item_emb, (ushort4*)ib, NI * 16);
  wfrag_k<<<20, 256, 0, stream>>>(gat_Wsrc, fbWsrc, 5);
  wfrag_k<<<20, 256, 0, stream>>>(gat_Wdst, fbWdst, 5);
  wfrag_k<<<8, 256, 0, stream>>>(W_out, fbWout, 2);
  wfrag_k<<<12, 256, 0, stream>>>(cheb_W, fbCheb, 3);
  wfrag_k<<<8, 256, 0, stream>>>(Wc, fbWc, 2);
  wfrag_k<<<8, 256, 0, stream>>>(Wsm, fbWsm, 2);
  wfrag_k<<<8, 256, 0, stream>>>(WpP, fbWpP, 2);
  wfrag_k<<<8, 256, 0, stream>>>(WpS, fbWpS, 2);

  // ---- 3 CSR groupings ----
  build_csr(rate_dst, rate_src, NR, NI, rp_rd, srt_rd, cursor, bsum, stream);
  build_csr(rate_src, rate_dst, NR, NU, rp_rs, srt_rs, cursor, bsum, stream);
  build_csr(link_dst, link_src, NL, NU, rp_ld, srt_ld, cursor, bsum, stream);

  // ---- projections (MFMA): fs0->B0, fd1->B1, fd2->B2, fd3->B3 ----
  mfma_g_k<1><<<MFMA_BLOCKS, 256, 0, stream>>>(ub, nullptr, nullptr,
      fbWsrc + 0 * FR, nullptr, nullptr, gat_bsrc + 0 * B64, B0, NU);
  mfma_g_k<1><<<MFMA_BLOCKS, 256, 0, stream>>>(ub, nullptr, nullptr,
      fbWdst + 1 * FR, nullptr, nullptr, gat_bdst + 1 * B64, B1, NU);
  mfma_g_k<1><<<MFMA_BLOCKS, 256, 0, stream>>>(ub, nullptr, nullptr,
      fbWdst + 2 * FR, nullptr, nullptr, gat_bdst + 2 * B64, B2, NU);
  mfma_g_k<1><<<MFMA_BLOCKS, 256, 0, stream>>>(ub, nullptr, nullptr,
      fbWdst + 3 * FR, nullptr, nullptr, gat_bdst + 3 * B64, B3, NU);
  // ---- item projections: fd0->B4, fs1->B5 ----
  mfma_g_k<1><<<MFMA_BLOCKS, 256, 0, stream>>>(ib, nullptr, nullptr,
      fbWdst + 0 * FR, nullptr, nullptr, gat_bdst + 0 * B64, B4, NI);
  mfma_g_k<1><<<MFMA_BLOCKS, 256, 0, stream>>>(ib, nullptr, nullptr,
      fbWsrc + 1 * FR, nullptr, nullptr, gat_bsrc + 1 * B64, B5, NI);

  // ---- gat0 -> B6 (h1_item) ; gat1 -> B7 (h2_user) ----
  gat32_k<<<EDGE_BLOCKS, 256, 0, stream>>>(B0, B4, gat_attn + 0 * B64, rp_rd, srt_rd, B6, NI);
  gat32_k<<<EDGE_BLOCKS, 256, 0, stream>>>(B5, B1, gat_attn + 1 * B64, rp_rs, srt_rs, B7, NU);

  // ---- fs2 = h1_item @ Ws2 -> B0 ; gat2 -> B4 (item_infl) ----
  mfma_g_k<1><<<MFMA_BLOCKS, 256, 0, stream>>>(B6, nullptr, nullptr,
      fbWsrc + 2 * FR, nullptr, nullptr, gat_bsrc + 2 * B64, B0, NI);
  gat32_k<<<EDGE_BLOCKS, 256, 0, stream>>>(B0, B2, gat_attn + 2 * B64, rp_rs, srt_rs, B4, NU);

  // ---- fs3 = h2_user @ Ws3 -> B5 ; gat3 -> B2 (social_item) ----
  mfma_g_k<1><<<MFMA_BLOCKS, 256, 0, stream>>>(B7, nullptr, nullptr,
      fbWsrc + 3 * FR, nullptr, nullptr, gat_bsrc + 3 * B64, B5, NU);
  gat32_k<<<EDGE_BLOCKS, 256, 0, stream>>>(B5, B3, gat_attn + 3 * B64, rp_ld, srt_ld, B2, NU);

  // ---- user_pref = [item_infl(B4), social_item(B2)] @ W_out -> B0 ----
  mfma_g_k<2><<<MFMA_BLOCKS, 256, 0, stream>>>(B4, B2, nullptr,
      fbWout + 0 * FR, fbWout + 1 * FR, nullptr, b_out, B0, NU);

  // ---- ChebConv(k=3): T1->B5, T2->B3, rst->B6 ----
  dinv_k<<<(NU + 255) / 256, 256, 0, stream>>>(rp_ld, dinv, NU);
  cheb32_k<1><<<EDGE_BLOCKS, 256, 0, stream>>>(ub, ub, nullptr, dinv, lam,
                                               rp_ld, srt_ld, B5, NU);
  cheb32_k<2><<<EDGE_BLOCKS, 256, 0, stream>>>(B5, ub, B5, dinv, lam,
                                               rp_ld, srt_ld, B3, NU);
  mfma_g_k<3><<<MFMA_BLOCKS, 256, 0, stream>>>(ub, B5, B3,
      fbCheb + 0 * FR, fbCheb + 1 * FR, fbCheb + 2 * FR, cheb_b, B6, NU);

  // ---- rst projections: fs4->B4, fd4->B2 ; gat4 -> B5 (user_social) ----
  mfma_g_k<1><<<MFMA_BLOCKS, 256, 0, stream>>>(B6, nullptr, nullptr,
      fbWsrc + 4 * FR, nullptr, nullptr, gat_bsrc + 4 * B64, B4, NU);
  mfma_g_k<1><<<MFMA_BLOCKS, 256, 0, stream>>>(B6, nullptr, nullptr,
      fbWdst + 4 * FR, nullptr, nullptr, gat_bdst + 4 * B64, B2, NU);
  gat32_k<<<EDGE_BLOCKS, 256, 0, stream>>>(B4, B2, gat_attn + 4 * B64, rp_ld, srt_ld, B5, NU);

  // ---- mutualistic: h_uP->B4, h_uS->B2 ----
  mfma_g_k<2><<<MFMA_BLOCKS, 256, 0, stream>>>(B0, ub, nullptr,
      fbWc + 0 * FR, fbWc + 1 * FR, nullptr, bc, B4, NU);
  mfma_g_k<2><<<MFMA_BLOCKS, 256, 0, stream>>>(B5, ub, nullptr,
      fbWsm + 0 * FR, fbWsm + 1 * FR, nullptr, bs, B2, NU);
  mut_k<<<(NU + 3) / 4, 256, 0, stream>>>(B4, B2, B3, B7, NU);  // mP->B3, mS->B7
  // h_new_P->B0, h_new_S->B5
  mfma_g_k<2><<<MFMA_BLOCKS, 256, 0, stream>>>(B3, B4, nullptr,
      fbWpP + 0 * FR, fbWpP + 1 * FR, nullptr, bpP, B0, NU);
  mfma_g_k<2><<<MFMA_BLOCKS, 256, 0, stream>>>(B7, B2, nullptr,
      fbWpS + 0 * FR, fbWpS + 1 * FR, nullptr, bpS, B5, NU);

  // ---- predictors ----
  float* out = (float*)d_out;
  dot32_k<<<EDGE_BLOCKS, 256, 0, stream>>>(B0, ib, rate_src, rate_dst, out, NR);
  dot32_k<<<EDGE_BLOCKS, 256, 0, stream>>>(B0, ib, neg_rate_src, neg_rate_dst, out + NR, NR);
  dot32_k<<<EDGE_BLOCKS, 256, 0, stream>>>(B5, ub, link_src, link_dst, out + 2 * (size_t)NR, NL);
  dot32_k<<<EDGE_BLOCKS, 256, 0, stream>>>(B5, ub, neg_link_src, neg_link_dst, out + 2 * (size_t)NR + NL, NL);
}